// Round 15
// baseline (295.607 us; speedup 1.0000x reference)
//
#include <hip/hip_runtime.h>

#define EPSV 1e-5f
#define HP 130            // padded H/W
#define HW 16384          // 128*128

typedef unsigned int u32;
typedef unsigned short bfu;                                    // bf16 storage
typedef __bf16 bf16x8 __attribute__((ext_vector_type(8)));
typedef float  f32x4  __attribute__((ext_vector_type(4)));

__device__ __forceinline__ bfu f2bf(float f){
  u32 u = __builtin_bit_cast(u32, f);
  return (bfu)((u + 0x7FFFu + ((u >> 16) & 1u)) >> 16);        // RNE
}
__device__ __forceinline__ float bf2f(bfu h){
  return __builtin_bit_cast(float, ((u32)h) << 16);
}
__device__ __forceinline__ f32x4 mfma16(bf16x8 a, bf16x8 b, f32x4 c){
  return __builtin_amdgcn_mfma_f32_16x16x32_bf16(a, b, c, 0, 0, 0);
}
__device__ __forceinline__ bf16x8 ldsfrag(const bfu* p){
  return __builtin_bit_cast(bf16x8, *(const uint4*)p);
}
// async global->LDS, 16B per lane; LDS dest = wave-uniform base + lane*16
__device__ __forceinline__ void gload_lds16(const uint4* g, uint4* l){
  __builtin_amdgcn_global_load_lds(
      (const __attribute__((address_space(1))) unsigned int*)g,
      (__attribute__((address_space(3))) unsigned int*)l, 16, 0, 0);
}

// ---------------- prep kernels ----------------

// zero only the halo borders of catT / w11T / out3T (interiors are fully written)
__global__ void k_zero_border(bfu* catT, bfu* w11T, bfu* out3T){
  int i = blockIdx.x*256 + threadIdx.x;      // 4*516 border cells
  if (i >= 4*516) return;
  int b = i/516, r = i - b*516;
  int hp, wpp;
  if (r < 130){ hp = 0; wpp = r; }
  else if (r < 260){ hp = 129; wpp = r - 130; }
  else { int r2 = r - 260; hp = 1 + (r2 >> 1); wpp = (r2 & 1)*129; }
  int pix = (b*HP + hp)*HP + wpp;
  uint4 z = {0,0,0,0};
  uint4* c4 = (uint4*)catT  + (size_t)pix*16;
  uint4* w4 = (uint4*)w11T  + (size_t)pix*8;
  uint4* o4 = (uint4*)out3T + (size_t)pix*8;
  #pragma unroll
  for (int k = 0; k < 16; ++k) c4[k] = z;
  #pragma unroll
  for (int k = 0; k < 8; ++k){ w4[k] = z; o4[k] = z; }
}

// weight reorders -> bf16.  A11[tap][och128][cin128]; A12[t][tap2][c64][j64]; A3[tap2][oc64][j64]
__global__ void k_prep_w(const float* __restrict__ w11w, const float* __restrict__ w21w,
                         const float* __restrict__ w12w, const float* __restrict__ w3w,
                         bfu* A11, bfu* A12, bfu* A3){
  const int total = 147456 + 331776 + 36864;
  for (int i = blockIdx.x*256 + threadIdx.x; i < total; i += gridDim.x*256){
    float v; bfu* dst;
    if (i < 147456){
      int tap = i >> 14, och = (i >> 7) & 127, cin = i & 127;
      v = (och < 64) ? w11w[(och*128 + cin)*9 + tap] : w21w[((och-64)*128 + cin)*9 + tap];
      dst = A11 + i;
    } else if (i < 147456 + 331776){
      int i2 = i - 147456;
      int g = i2 >> 12, t = g/9, tap2 = g%9;
      int c = (i2 >> 6) & 63, j = i2 & 63;
      v = w12w[((c*9 + t)*64 + j)*9 + tap2];
      dst = A12 + i2;
    } else {
      int i3 = i - (147456 + 331776);
      int tap2 = i3 >> 12, oc = (i3 >> 6) & 63, j = i3 & 63;
      v = w3w[(oc*64 + j)*9 + tap2];
      dst = A3 + i3;
    }
    *dst = f2bf(v);
  }
}

// catT interior: NHWC bf16 [b][130][130][128ch]; coalesced read via LDS transpose
__global__ void k_prep_cat(const float* __restrict__ inp, const float* __restrict__ wgt, bfu* catT){
  __shared__ bfu lds[128*136];
  int b = blockIdx.y, h = blockIdx.x;        // grid (128,4)
  int t = threadIdx.x;
  int w = t & 127, c0 = t >> 7;
  #pragma unroll 1
  for (int c = c0; c < 128; c += 2){
    const float* src = (c < 64) ? inp + ((b*64 + c)*128 + h)*128
                                : wgt + ((b*64 + (c-64))*128 + h)*128;
    lds[w*136 + c] = f2bf(src[w]);
  }
  __syncthreads();
  uint4* dst = (uint4*)catT;
  #pragma unroll
  for (int k = 0; k < 8; ++k){
    int idx = k*256 + t;
    int pix = idx >> 4, sub = idx & 15;
    uint4 v = *(const uint4*)&lds[pix*136 + sub*8];
    dst[(((b*HP + h+1)*HP) + (pix+1))*16 + sub] = v;
  }
}

// ---------------- k1: conv11 + conv21 (implicit GEMM, M=128, K=9*128) ----------------
__global__ __launch_bounds__(256) void k1_conv(
    const bfu* __restrict__ catT, const bfu* __restrict__ A11,
    const float* __restrict__ b11, const float* __restrict__ b21,
    bfu* __restrict__ w11T, float* __restrict__ poolP){
  __shared__ bfu ldsC[180*128];              // 46,080 B, swizzled cat tile
  __shared__ bfu ldsA[2*8192];               // 32,768 B: 2 bufs x 1024 uint4
  __shared__ float statsF[128];              //    512 B
  int tid = threadIdx.x;
  int b = blockIdx.y, tile = blockIdx.x;     // 0..127
  int h0 = (tile >> 3)*8, w0 = (tile & 7)*16;

  int wid = tid >> 6, l = tid & 63, lg = l >> 4, pc = l & 15;
  int wm = wid >> 1, wn = wid & 1;
  int pcT = tid & 15, lgT = (tid >> 4) & 3;

  const uint4* A4 = (const uint4*)A11;       // [tap][row128][16]
  uint4* ldsA4 = (uint4*)ldsA;

  #pragma unroll
  for (int k = 0; k < 4; ++k){
    int q = k*4 + wid;
    int row = (q >> 1)*16 + pcT;
    gload_lds16(A4 + row*16 + (q&1)*4 + lgT, ldsA4 + k*256 + wid*64);
  }

  const uint4* catT4 = (const uint4*)catT;
  for (int s = tid; s < 180*16; s += 256){
    int cell = s >> 4, sub = s & 15;
    int th = cell/18, tw = cell - th*18;
    uint4 v = catT4[(((b*HP + h0+th)*HP) + (w0+tw))*16 + sub];
    *(uint4*)&ldsC[cell*128 + ((sub*8) ^ ((cell&7)<<3))] = v;
  }
  __syncthreads();

  f32x4 acc[4][4];
  #pragma unroll
  for (int i = 0; i < 4; ++i)
    #pragma unroll
    for (int j = 0; j < 4; ++j) acc[i][j] = f32x4{0.f,0.f,0.f,0.f};

  int cur = 0;
  #pragma unroll 1
  for (int cc = 0; cc < 18; ++cc){
    int tap = cc >> 1, p = cc & 1;
    if (cc < 17){
      int cc1 = cc + 1, tap1 = cc1 >> 1, p1 = cc1 & 1;
      #pragma unroll
      for (int k = 0; k < 4; ++k){
        int q = k*4 + wid;
        int row = (q >> 1)*16 + pcT;
        gload_lds16(A4 + tap1*2048 + row*16 + p1*8 + (q&1)*4 + lgT,
                    ldsA4 + (cur^1)*1024 + k*256 + wid*64);
      }
    }
    int kh = (tap >= 6) ? 2 : ((tap >= 3) ? 1 : 0);
    int kw = tap - kh*3;
    #pragma unroll
    for (int jq = 0; jq < 2; ++jq){
      int jc = p*2 + jq;
      bf16x8 a[4], bb[4];
      #pragma unroll
      for (int fm = 0; fm < 4; ++fm)
        a[fm] = __builtin_bit_cast(bf16x8, ldsA4[cur*1024 + ((wm*4 + fm)*2 + jq)*64 + l]);
      #pragma unroll
      for (int fn = 0; fn < 4; ++fn){
        int cell = (wn*4 + fn + kh)*18 + (pc + kw);
        bb[fn] = ldsfrag(&ldsC[cell*128 + ((jc*32 + lg*8) ^ ((cell&7)<<3))]);
      }
      #pragma unroll
      for (int fm = 0; fm < 4; ++fm)
        #pragma unroll
        for (int fn = 0; fn < 4; ++fn)
          acc[fm][fn] = mfma16(a[fm], bb[fn], acc[fm][fn]);
    }
    __syncthreads();
    cur ^= 1;
  }

  if (wm == 0){
    #pragma unroll
    for (int fm = 0; fm < 4; ++fm)
      #pragma unroll
      for (int r = 0; r < 4; ++r){
        int och = fm*16 + lg*4 + r;
        float bias = b11[och];
        #pragma unroll
        for (int fn = 0; fn < 4; ++fn){
          float v = acc[fm][fn][r] + bias;
          v = v > 0.f ? v : 0.f;
          int px = wn*64 + fn*16 + pc;
          ldsC[px*72 + och] = f2bf(v);
        }
      }
  } else {
    #pragma unroll
    for (int fm = 0; fm < 4; ++fm)
      #pragma unroll
      for (int r = 0; r < 4; ++r){
        int cw = fm*16 + lg*4 + r;
        float bias = b21[cw];
        float s = 0.f;
        #pragma unroll
        for (int fn = 0; fn < 4; ++fn){
          float v = acc[fm][fn][r] + bias;
          s += (v > 0.f ? v : 0.f);
        }
        s += __shfl_xor(s,1); s += __shfl_xor(s,2); s += __shfl_xor(s,4); s += __shfl_xor(s,8);
        if (pc == 0) statsF[wn*64 + cw] = s;
      }
  }
  __syncthreads();

  if (wid < 2){
    int px = tid;
    int h = h0 + (px >> 4), w = w0 + (px & 15);
    uint4* dst = (uint4*)w11T + (((b*HP + h+1)*HP) + (w+1))*8;
    const uint4* srcT = (const uint4*)&ldsC[px*72];
    #pragma unroll
    for (int k = 0; k < 8; ++k) dst[k] = srcT[k];
  }
  if (tid < 64)
    poolP[(b*128 + tile)*64 + tid] = statsF[tid] + statsF[64 + tid];
}

// ---------------- k2: pooled mean + w22 GEMV (bf16 output) ----------------
__global__ void k2a_pool(const float* __restrict__ poolP, float* pooled){
  int t = threadIdx.x;
  int b = t >> 6, c = t & 63;
  float s = 0.f;
  for (int tile = 0; tile < 128; ++tile) s += poolP[(b*128 + tile)*64 + c];
  pooled[t] = s * (1.f/16384.f);
}

__global__ void k2b_w22(const float* __restrict__ pooled, const float* __restrict__ W22,
                        const float* __restrict__ b22, bfu* __restrict__ w22bf){
  __shared__ float pl[64];
  int b = blockIdx.x >> 4, og = blockIdx.x & 15;
  if (threadIdx.x < 64) pl[threadIdx.x] = pooled[b*64 + threadIdx.x];
  __syncthreads();
  int o = og*256 + threadIdx.x;
  float acc = b22[o];
  #pragma unroll 4
  for (int c = 0; c < 64; ++c) acc += pl[c]*W22[o*64 + c];
  w22bf[b*4096 + o] = f2bf(acc);
}

// ---------------- k3: fused conv12 + local_conv, EVEN jc-split partials ----------------
// r13 post-mortem: k3 is 91% LDS-ISSUE bound (288 b128/chunk/CU ~ 3456 cyc vs
// 3800 observed). Fix: fn=4 amortization (24 reads/chunk/wave vs 36) while
// keeping 512 blocks / 2 blk/CU via EVEN K-split: block g computes jc=g only
// (32 of 64 w11 channels). Linearity: oacc = [sum inv*(y^0+b)] + [sum inv*y^1];
// g=0 adds bias, g=1 doesn't. ldsW keeps the proven 128B-cell swizzle (only
// g-half staged/read). LDS 68.4KB -> 2 blocks/CU; 27 chunks, 27 barriers.
__global__ __launch_bounds__(256) void k3_fused(
    const bfu* __restrict__ w11T, const bfu* __restrict__ catT,
    const bfu* __restrict__ A12, const float* __restrict__ b12,
    float* __restrict__ out1, float* __restrict__ outP){
  __shared__ bfu ldsW[324*64];               // 41,472 B (only g-half filled)
  __shared__ bfu ldsA[2*3*2048];             // 24,576 B: 2 bufs x 3 half-slices
  __shared__ float b12f[576];                //  2,304 B   (total 68,352 B)
  int tid = threadIdx.x;
  int b = blockIdx.y, tile = blockIdx.x, g = blockIdx.z;
  int h0 = (tile >> 3)*16, w0 = (tile & 7)*16;

  int wid = tid >> 6, l = tid & 63, lg = l >> 4, pc = l & 15;
  int w4 = wid*4;
  int g4 = g*4;
  float* outp = g ? outP : out1;

  // A12 half-slice staging: slot tid of each 256-slot slice holds
  // A[c = (tid>>6)*16 + (tid&15)][j = g*32 + ((tid>>4)&3)*8 ..+8]
  const uint4* A4 = (const uint4*)A12;
  uint4* ldsA4 = (uint4*)ldsA;
  int srcA = ((tid >> 6)*16 + (tid & 15))*8 + g4 + ((tid >> 4) & 3);
  uint4* dstBase = ldsA4 + wid*64;           // wave-uniform; lane*16B implicit

  // prologue: chunk 0 (tap2 = 0,1,2) into buf 0
  #pragma unroll
  for (int s = 0; s < 3; ++s)
    gload_lds16(A4 + (size_t)s*512 + srcA, dstBase + s*256);

  // stage g-half of w11 tile (proven swizzle, sub = g4+q)
  const uint4* w11T4 = (const uint4*)w11T;
  for (int s = tid; s < 324*4; s += 256){
    int cell = s >> 2, q = s & 3;
    int th = cell/18, tw = cell - th*18;
    uint4 v = w11T4[(((b*HP + h0+th)*HP) + (w0+tw))*8 + g4 + q];
    int sub = g4 + q;
    *(uint4*)&ldsW[cell*64 + ((sub*8) ^ ((cell&7)<<3))] = v;
  }
  for (int i = tid; i < 576; i += 256) b12f[i] = b12[i];
  __syncthreads();                           // ldsW + chunk 0 ready

  f32x4 oacc[4][4];
  #pragma unroll
  for (int i = 0; i < 4; ++i)
    #pragma unroll
    for (int j = 0; j < 4; ++j) oacc[i][j] = f32x4{0.f,0.f,0.f,0.f};
  f32x4 y[4][4];
  int cur = 0;
  int boff = g*32 + lg*8;                    // B-frag bfu offset within cell

  #pragma unroll 1
  for (int cc = 0; cc < 27; ++cc){
    int tt = cc/3, m3 = cc - tt*3;           // kh = m3, kw = t3
    if (cc < 26){                            // issue next chunk BEFORE compute
      const uint4* sb = A4 + (size_t)((cc+1)*3)*512 + srcA;
      uint4* db = ldsA4 + (cur^1)*768 + wid*64;
      #pragma unroll
      for (int s = 0; s < 3; ++s)
        gload_lds16(sb + s*512, db + s*256);
    }
    if (m3 == 0){
      #pragma unroll
      for (int i = 0; i < 4; ++i)
        #pragma unroll
        for (int j = 0; j < 4; ++j) y[i][j] = f32x4{0.f,0.f,0.f,0.f};
    }
    #pragma unroll
    for (int t3 = 0; t3 < 3; ++t3){
      bf16x8 a[4], bbf[4];
      #pragma unroll
      for (int fm = 0; fm < 4; ++fm)
        a[fm] = __builtin_bit_cast(bf16x8, ldsA4[cur*768 + t3*256 + fm*64 + l]);
      #pragma unroll
      for (int fn = 0; fn < 4; ++fn){
        int cell = (w4 + fn + m3)*18 + (pc + t3);
        bbf[fn] = ldsfrag(&ldsW[cell*64 + (boff ^ ((cell&7)<<3))]);
      }
      #pragma unroll
      for (int fm = 0; fm < 4; ++fm)
        #pragma unroll
        for (int fn = 0; fn < 4; ++fn)
          y[fm][fn] = mfma16(a[fm], bbf[fn], y[fm][fn]);
    }
    __syncthreads();                         // readers done + next chunk drained
    if (m3 == 2){                            // tt complete: fold local_conv tap
      int dh = tt/3, dw = tt - dh*3;
      #pragma unroll
      for (int fn = 0; fn < 4; ++fn){
        const bfu* bp = catT + ((size_t)((b*HP + h0 + w4 + fn + dh)*HP) + (w0 + pc + dw))*128 + lg*4;
        #pragma unroll
        for (int fm = 0; fm < 4; ++fm){
          ushort4 iv = *(const ushort4*)(bp + fm*16);
          float i0 = bf2f(iv.x), i1 = bf2f(iv.y), i2 = bf2f(iv.z), i3 = bf2f(iv.w);
          int c = fm*16 + lg*4;
          float bz0 = g ? 0.f : b12f[(c+0)*9 + tt];
          float bz1 = g ? 0.f : b12f[(c+1)*9 + tt];
          float bz2 = g ? 0.f : b12f[(c+2)*9 + tt];
          float bz3 = g ? 0.f : b12f[(c+3)*9 + tt];
          oacc[fm][fn][0] += i0 * (y[fm][fn][0] + bz0);
          oacc[fm][fn][1] += i1 * (y[fm][fn][1] + bz1);
          oacc[fm][fn][2] += i2 * (y[fm][fn][2] + bz2);
          oacc[fm][fn][3] += i3 * (y[fm][fn][3] + bz3);
        }
      }
    }
    cur ^= 1;
  }

  // write partial output (no stats; k3b computes them on the sum)
  #pragma unroll
  for (int fm = 0; fm < 4; ++fm)
    #pragma unroll
    for (int r = 0; r < 4; ++r){
      int c = fm*16 + lg*4 + r;
      #pragma unroll
      for (int fn = 0; fn < 4; ++fn)
        outp[((b*64 + c)*128 + h0 + w4 + fn)*128 + (w0 + pc)] = oacc[fm][fn][r];
    }
}

// ---------------- k3b: BN1 stats over (out1 + outP) ----------------
__global__ __launch_bounds__(256) void k3b_stat(
    const float* __restrict__ out1, const float* __restrict__ outP, float* __restrict__ st){
  __shared__ float red[8];
  int bc = blockIdx.x, t = threadIdx.x;
  const float4* p1 = (const float4*)(out1 + (size_t)bc*HW);
  const float4* p2 = (const float4*)(outP + (size_t)bc*HW);
  float s = 0.f, ss = 0.f;
  #pragma unroll 4
  for (int i = t; i < 4096; i += 256){
    float4 a = p1[i], q = p2[i];
    float v0 = a.x+q.x, v1 = a.y+q.y, v2 = a.z+q.z, v3 = a.w+q.w;
    s  += v0+v1+v2+v3;
    ss += v0*v0+v1*v1+v2*v2+v3*v3;
  }
  #pragma unroll
  for (int m = 1; m < 64; m <<= 1){ s += __shfl_xor(s, m); ss += __shfl_xor(ss, m); }
  if ((t & 63) == 0){ red[(t >> 6)*2] = s; red[(t >> 6)*2 + 1] = ss; }
  __syncthreads();
  if (t == 0){
    s  = red[0] + red[2] + red[4] + red[6];
    ss = red[1] + red[3] + red[5] + red[7];
    st[bc*2] = s; st[bc*2 + 1] = ss;
  }
}

// ---------------- BN stat reduce (coalesced, 256 threads) ----------------
__global__ void k_bnstat(const float* __restrict__ st, int nblk, float n,
                         const float* __restrict__ g, const float* __restrict__ bb, float* bn){
  __shared__ float red[512];
  int tid = threadIdx.x;
  int c = tid & 63, kk = tid >> 6;           // 4 k-groups
  float s = 0.f, ss = 0.f;
  for (int k = kk; k < nblk; k += 4){
    float2 v = *(const float2*)&st[(k*64 + c)*2];
    s += v.x; ss += v.y;
  }
  red[tid*2] = s; red[tid*2 + 1] = ss;
  __syncthreads();
  if (tid < 64){
    #pragma unroll
    for (int q = 1; q < 4; ++q){ s += red[(q*64 + tid)*2]; ss += red[(q*64 + tid)*2 + 1]; }
    float mean = s/n, var = ss/n - mean*mean;
    float a = g[tid]*rsqrtf(var + EPSV);
    bn[tid*2] = a; bn[tid*2 + 1] = bb[tid] - mean*a;
  }
}

// ---------------- k4: einsum as MFMA GEMM, x = out1 + outP ----------------
// outP aliases out2 (d_out) -- safe: per-block stage-then-write, disjoint px.
__global__ __launch_bounds__(256) void k4_einsum(
    const float* __restrict__ out1, const float* __restrict__ outP,
    const bfu* __restrict__ w22bf, const float* __restrict__ bn1,
    float* __restrict__ out2, float* __restrict__ st2){
  __shared__ bfu ldsX[256*72];               // [px][j], 144B rows
  __shared__ float a1[64], be1[64];
  __shared__ float wp[512];
  int tid = threadIdx.x;
  int b = blockIdx.y, chunk = blockIdx.x;    // 64 chunks of 256 px
  if (tid < 64){ a1[tid] = bn1[tid*2]; be1[tid] = bn1[tid*2 + 1]; }
  __syncthreads();
  int p0 = chunk*256;

  {
    int px = tid;
    const float* src1 = out1 + (size_t)(b*64)*HW + p0 + px;
    const float* src2 = outP + (size_t)(b*64)*HW + p0 + px;
    #pragma unroll 1
    for (int j0 = 0; j0 < 64; j0 += 4){
      float x0 = src1[(j0+0)*HW] + src2[(j0+0)*HW]; x0 = a1[j0+0]*x0 + be1[j0+0]; x0 = x0 > 0.f ? x0 : 0.f;
      float x1 = src1[(j0+1)*HW] + src2[(j0+1)*HW]; x1 = a1[j0+1]*x1 + be1[j0+1]; x1 = x1 > 0.f ? x1 : 0.f;
      float x2 = src1[(j0+2)*HW] + src2[(j0+2)*HW]; x2 = a1[j0+2]*x2 + be1[j0+2]; x2 = x2 > 0.f ? x2 : 0.f;
      float x3 = src1[(j0+3)*HW] + src2[(j0+3)*HW]; x3 = a1[j0+3]*x3 + be1[j0+3]; x3 = x3 > 0.f ? x3 : 0.f;
      ushort4 pk; pk.x = f2bf(x0); pk.y = f2bf(x1); pk.z = f2bf(x2); pk.w = f2bf(x3);
      *(ushort4*)&ldsX[px*72 + j0] = pk;
    }
  }
  __syncthreads();

  int wid = tid >> 6, l = tid & 63, lg = l >> 4, pc = l & 15;
  const uint4* W4 = (const uint4*)w22bf;
  f32x4 acc[4][4];
  #pragma unroll
  for (int i = 0; i < 4; ++i)
    #pragma unroll
    for (int j = 0; j < 4; ++j) acc[i][j] = f32x4{0.f,0.f,0.f,0.f};

  #pragma unroll
  for (int jc = 0; jc < 2; ++jc){
    bf16x8 a[4], bb[4];
    #pragma unroll
    for (int fm = 0; fm < 4; ++fm)
      a[fm] = __builtin_bit_cast(bf16x8, W4[b*512 + (fm*16 + pc)*8 + jc*4 + lg]);
    #pragma unroll
    for (int fn = 0; fn < 4; ++fn)
      bb[fn] = ldsfrag(&ldsX[(wid*64 + fn*16 + pc)*72 + jc*32 + lg*8]);
    #pragma unroll
    for (int fm = 0; fm < 4; ++fm)
      #pragma unroll
      for (int fn = 0; fn < 4; ++fn)
        acc[fm][fn] = mfma16(a[fm], bb[fn], acc[fm][fn]);
  }

  #pragma unroll
  for (int fm = 0; fm < 4; ++fm)
    #pragma unroll
    for (int r = 0; r < 4; ++r){
      int i = fm*16 + lg*4 + r;
      float s = 0.f, ss = 0.f;
      #pragma unroll
      for (int fn = 0; fn < 4; ++fn){
        int px = wid*64 + fn*16 + pc;
        float v = acc[fm][fn][r];
        out2[(b*64 + i)*HW + p0 + px] = v;
        s += v; ss += v*v;
      }
      s += __shfl_xor(s,1); s += __shfl_xor(s,2); s += __shfl_xor(s,4); s += __shfl_xor(s,8);
      ss += __shfl_xor(ss,1); ss += __shfl_xor(ss,2); ss += __shfl_xor(ss,4); ss += __shfl_xor(ss,8);
      if (pc == 0){ wp[(wid*64 + i)*2] = s; wp[(wid*64 + i)*2 + 1] = ss; }
    }
  __syncthreads();
  if (tid < 64){
    float s = 0.f, ss = 0.f;
    #pragma unroll
    for (int w = 0; w < 4; ++w){ s += wp[(w*64 + tid)*2]; ss += wp[(w*64 + tid)*2 + 1]; }
    int blin = b*64 + chunk;
    st2[(blin*64 + tid)*2] = s; st2[(blin*64 + tid)*2 + 1] = ss;
  }
}

// ---------------- k4c: out3T = relu(bn2(out2)) NHWC bf16, coalesced via LDS transpose ----------------
__global__ void k4c_out3(const float* __restrict__ out2, const float* __restrict__ bn2, bfu* out3T){
  __shared__ bfu lds[128*72];
  int b = blockIdx.y, h = blockIdx.x;        // grid (128,4)
  int t = threadIdx.x;
  int px = t & 127, ch = (t >> 7)*32;
  #pragma unroll 1
  for (int cc = 0; cc < 32; cc += 4){
    int c = ch + cc;
    float x0 = out2[((b*64 + c+0) << 14) + (h << 7) + px];
    float x1 = out2[((b*64 + c+1) << 14) + (h << 7) + px];
    float x2 = out2[((b*64 + c+2) << 14) + (h << 7) + px];
    float x3 = out2[((b*64 + c+3) << 14) + (h << 7) + px];
    x0 = bn2[(c+0)*2]*x0 + bn2[(c+0)*2+1]; x0 = x0 > 0.f ? x0 : 0.f;
    x1 = bn2[(c+1)*2]*x1 + bn2[(c+1)*2+1]; x1 = x1 > 0.f ? x1 : 0.f;
    x2 = bn2[(c+2)*2]*x2 + bn2[(c+2)*2+1]; x2 = x2 > 0.f ? x2 : 0.f;
    x3 = bn2[(c+3)*2]*x3 + bn2[(c+3)*2+1]; x3 = x3 > 0.f ? x3 : 0.f;
    ushort4 pk; pk.x = f2bf(x0); pk.y = f2bf(x1); pk.z = f2bf(x2); pk.w = f2bf(x3);
    *(ushort4*)&lds[px*72 + c] = pk;
  }
  __syncthreads();
  uint4* dst = (uint4*)out3T;
  #pragma unroll
  for (int k = 0; k < 4; ++k){
    int idx = k*256 + t;                     // 0..1023
    int pix = idx >> 3, sub = idx & 7;
    uint4 v = *(const uint4*)&lds[pix*72 + sub*8];
    dst[((size_t)(b*HP + h+1)*HP + (pix+1))*8 + sub] = v;
  }
}

// ---------------- k5: conv3 (implicit GEMM M=64,K=576), 512 blocks + BN3 stats ----------------
__global__ __launch_bounds__(256) void k5_conv3(
    const bfu* __restrict__ out3T, const bfu* __restrict__ A3,
    float* __restrict__ outc, float* __restrict__ st3){
  __shared__ bfu lds[180*72];                // 10x18 cells, 25,920 B
  __shared__ float wp[512];
  int tid = threadIdx.x;
  int b = blockIdx.y, tile = blockIdx.x;     // 0..127
  int h0 = (tile >> 3)*8, w0 = (tile & 7)*16;
  const uint4* src4 = (const uint4*)out3T;
  for (int s = tid; s < 180*8; s += 256){
    int cell = s >> 3, sub = s & 7;
    int th = cell/18, tw = cell - th*18;
    *(uint4*)&lds[cell*72 + sub*8] = src4[(((b*HP + h0+th)*HP) + (w0+tw))*8 + sub];
  }
  __syncthreads();

  int wid = tid >> 6, l = tid & 63, lg = l >> 4, pc = l & 15;
  f32x4 acc[4][2];
  #pragma unroll
  for (int i = 0; i < 4; ++i){ acc[i][0] = f32x4{0.f,0.f,0.f,0.f}; acc[i][1] = f32x4{0.f,0.f,0.f,0.f}; }
  const uint4* A4 = (const uint4*)A3;
  #pragma unroll 3
  for (int tap2 = 0; tap2 < 9; ++tap2){
    int kh = tap2/3, kw = tap2 - kh*3;
    #pragma unroll
    for (int jc = 0; jc < 2; ++jc){
      bf16x8 a[4], bb[2];
      #pragma unroll
      for (int fm = 0; fm < 4; ++fm)
        a[fm] = __builtin_bit_cast(bf16x8, A4[tap2*512 + (fm*16 + pc)*8 + jc*4 + lg]);
      #pragma unroll
      for (int fn = 0; fn < 2; ++fn){
        int cell = (wid*2 + fn + kh)*18 + (pc + kw);
        bb[fn] = ldsfrag(&lds[cell*72 + jc*32 + lg*8]);
      }
      #pragma unroll
      for (int fm = 0; fm < 4; ++fm)
        #pragma unroll
        for (int fn = 0; fn < 2; ++fn)
          acc[fm][fn] = mfma16(a[fm], bb[fn], acc[fm][fn]);
    }
  }
  #pragma unroll
  for (int fm = 0; fm < 4; ++fm)
    #pragma unroll
    for (int r = 0; r < 4; ++r){
      int c = fm*16 + lg*4 + r;
      float s = 0.f, ss = 0.f;
      #pragma unroll
      for (int fn = 0; fn < 2; ++fn){
        int pr = wid*2 + fn;
        float v = acc[fm][fn][r];
        outc[((b*64 + c)*128 + h0 + pr)*128 + (w0 + pc)] = v;
        s += v; ss += v*v;
      }
      s += __shfl_xor(s,1); s += __shfl_xor(s,2); s += __shfl_xor(s,4); s += __shfl_xor(s,8);
      ss += __shfl_xor(ss,1); ss += __shfl_xor(ss,2); ss += __shfl_xor(ss,4); ss += __shfl_xor(ss,8);
      if (pc == 0){ wp[(wid*64 + c)*2] = s; wp[(wid*64 + c)*2 + 1] = ss; }
    }
  __syncthreads();
  if (tid < 64){
    float s = 0.f, ss = 0.f;
    #pragma unroll
    for (int w = 0; w < 4; ++w){ s += wp[(w*64 + tid)*2]; ss += wp[(w*64 + tid)*2 + 1]; }
    int blin = b*128 + tile;
    st3[(blin*64 + tid)*2] = s; st3[(blin*64 + tid)*2 + 1] = ss;
  }
}

// ---------------- k6: final relu(bn3(conv3_pre)) in place, float4 ----------------
__global__ void k6_final(float4* __restrict__ out, const float* __restrict__ bn3){
  const int total4 = 4*64*HW/4;              // 1,048,576
  for (int i = blockIdx.x*256 + threadIdx.x; i < total4; i += gridDim.x*256){
    int c = (i >> 12) & 63;
    float a = bn3[c*2], be = bn3[c*2 + 1];
    float4 x = out[i];
    x.x = a*x.x + be; x.x = x.x > 0.f ? x.x : 0.f;
    x.y = a*x.y + be; x.y = x.y > 0.f ? x.y : 0.f;
    x.z = a*x.z + be; x.z = x.z > 0.f ? x.z : 0.f;
    x.w = a*x.w + be; x.w = x.w > 0.f ? x.w : 0.f;
    out[i] = x;
  }
}

extern "C" void kernel_launch(void* const* d_in, const int* in_sizes, int n_in,
                              void* d_out, int out_size, void* d_ws, size_t ws_size,
                              hipStream_t stream){
  const float* inp  = (const float*)d_in[0];
  const float* wgt  = (const float*)d_in[1];
  const float* w11w = (const float*)d_in[2];
  const float* b11  = (const float*)d_in[3];
  const float* w12w = (const float*)d_in[4];
  const float* b12  = (const float*)d_in[5];
  const float* w21w = (const float*)d_in[6];
  const float* b21  = (const float*)d_in[7];
  const float* W22  = (const float*)d_in[8];
  const float* b22  = (const float*)d_in[9];
  const float* lg   = (const float*)d_in[10];
  const float* lb   = (const float*)d_in[11];
  const float* brg  = (const float*)d_in[12];
  const float* brb  = (const float*)d_in[13];
  const float* w3w  = (const float*)d_in[14];
  const float* c3g  = (const float*)d_in[15];
  const float* c3b  = (const float*)d_in[16];

  if (ws_size < 53200000) return;

  char* ws = (char*)d_ws;
  bfu*   catT  = (bfu*)(ws);                     // 17,305,600
  bfu*   w11T  = (bfu*)(ws + 17305600);          //  8,652,800
  bfu*   out3T = (bfu*)(ws + 25958400);          //  8,652,800
  bfu*   A11   = (bfu*)(ws + 34611200);          //    294,912
  bfu*   A12   = (bfu*)(ws + 34906112);          //    663,552
  bfu*   A3    = (bfu*)(ws + 35569664);          //     73,728
  float* out1  = (float*)(ws + 35643392);        // 16,777,216
  float* poolP = (float*)(ws + 52420608);        //    131,072
  float* pooled= (float*)(ws + 52551680);        //      1,024
  bfu*   w22bf = (bfu*)(ws + 52552704);          //     32,768
  float* st13  = (float*)(ws + 52585472);        //    262,144 (st1 then st3 — disjoint in time)
  float* bn1   = (float*)(ws + 52847616);        //        512
  float* st2   = (float*)(ws + 52848128);        //    131,072
  float* bn2   = (float*)(ws + 52979200);        //        512
  float* bn3   = (float*)(ws + 52979712);        //        512
  float* outF  = (float*)d_out;                  // k3 partial(g=1), then out2, then out4

  k_zero_border<<<dim3(9),  dim3(256), 0, stream>>>(catT, w11T, out3T);
  k_prep_w  <<<dim3(512),  dim3(256), 0, stream>>>(w11w, w21w, w12w, w3w, A11, A12, A3);
  k_prep_cat<<<dim3(128,4),dim3(256), 0, stream>>>(inp, wgt, catT);
  k1_conv   <<<dim3(128,4),dim3(256), 0, stream>>>(catT, A11, b11, b21, w11T, poolP);
  k2a_pool  <<<dim3(1),    dim3(256), 0, stream>>>(poolP, pooled);
  k2b_w22   <<<dim3(64),   dim3(256), 0, stream>>>(pooled, W22, b22, w22bf);
  k3_fused  <<<dim3(64,4,2),dim3(256),0, stream>>>(w11T, catT, A12, b12, out1, outF);
  k3b_stat  <<<dim3(256),  dim3(256), 0, stream>>>(out1, outF, st13);
  k_bnstat  <<<dim3(1),    dim3(256), 0, stream>>>(st13, 4, 65536.f, lg, lb, bn1);
  k4_einsum <<<dim3(64,4), dim3(256), 0, stream>>>(out1, outF, w22bf, bn1, outF, st2);
  k_bnstat  <<<dim3(1),    dim3(256), 0, stream>>>(st2, 256, 65536.f, brg, brb, bn2);
  k4c_out3  <<<dim3(128,4),dim3(256), 0, stream>>>(outF, bn2, out3T);
  k5_conv3  <<<dim3(128,4),dim3(256), 0, stream>>>(out3T, A3, outF, st13);
  k_bnstat  <<<dim3(1),    dim3(256), 0, stream>>>(st13, 512, 65536.f, c3g, c3b, bn3);
  k6_final  <<<dim3(1024), dim3(256), 0, stream>>>((float4*)outF, bn3);
}

// Round 16
// 278.669 us; speedup vs baseline: 1.0608x; 1.0608x over previous
//
#include <hip/hip_runtime.h>

#define EPSV 1e-5f
#define HP 130            // padded H/W
#define HW 16384          // 128*128

typedef unsigned int u32;
typedef unsigned short bfu;                                    // bf16 storage
typedef __bf16 bf16x8 __attribute__((ext_vector_type(8)));
typedef float  f32x4  __attribute__((ext_vector_type(4)));

__device__ __forceinline__ bfu f2bf(float f){
  u32 u = __builtin_bit_cast(u32, f);
  return (bfu)((u + 0x7FFFu + ((u >> 16) & 1u)) >> 16);        // RNE
}
__device__ __forceinline__ float bf2f(bfu h){
  return __builtin_bit_cast(float, ((u32)h) << 16);
}
__device__ __forceinline__ f32x4 mfma16(bf16x8 a, bf16x8 b, f32x4 c){
  return __builtin_amdgcn_mfma_f32_16x16x32_bf16(a, b, c, 0, 0, 0);
}
__device__ __forceinline__ bf16x8 ldsfrag(const bfu* p){
  return __builtin_bit_cast(bf16x8, *(const uint4*)p);
}
// async global->LDS, 16B per lane; LDS dest = wave-uniform base + lane*16
__device__ __forceinline__ void gload_lds16(const uint4* g, uint4* l){
  __builtin_amdgcn_global_load_lds(
      (const __attribute__((address_space(1))) unsigned int*)g,
      (__attribute__((address_space(3))) unsigned int*)l, 16, 0, 0);
}

// ---------------- k_prep: zero borders + weight reorder + catT build (fused) ----------------
// grid (134,4): bx<128 -> prep_cat row (h=bx, b=by); bx>=128 -> 24 role blocks
// grid-striding zero-border (2064 items) then prep_w (516,096 items).
__global__ __launch_bounds__(256) void k_prep(
    const float* __restrict__ inp, const float* __restrict__ wgt,
    const float* __restrict__ w11w, const float* __restrict__ w21w,
    const float* __restrict__ w12w, const float* __restrict__ w3w,
    bfu* catT, bfu* A11, bfu* A12, bfu* A3, bfu* w11T, bfu* out3T){
  __shared__ bfu lds[128*136];
  int bx = blockIdx.x, by = blockIdx.y;
  int t = threadIdx.x;

  if (bx < 128){                             // ---- prep_cat ----
    int b = by, h = bx;
    int w = t & 127, c0 = t >> 7;
    #pragma unroll 1
    for (int c = c0; c < 128; c += 2){
      const float* src = (c < 64) ? inp + ((b*64 + c)*128 + h)*128
                                  : wgt + ((b*64 + (c-64))*128 + h)*128;
      lds[w*136 + c] = f2bf(src[w]);
    }
    __syncthreads();
    uint4* dst = (uint4*)catT;
    #pragma unroll
    for (int k = 0; k < 8; ++k){
      int idx = k*256 + t;
      int pix = idx >> 4, sub = idx & 15;
      uint4 v = *(const uint4*)&lds[pix*136 + sub*8];
      dst[(((b*HP + h+1)*HP) + (pix+1))*16 + sub] = v;
    }
    return;
  }

  int r = (bx - 128)*4 + by;                 // 0..23
  const int STR = 24*256;
  // ---- zero borders ----
  for (int i = r*256 + t; i < 4*516; i += STR){
    int b = i/516, rr = i - b*516;
    int hp, wpp;
    if (rr < 130){ hp = 0; wpp = rr; }
    else if (rr < 260){ hp = 129; wpp = rr - 130; }
    else { int r2 = rr - 260; hp = 1 + (r2 >> 1); wpp = (r2 & 1)*129; }
    int pix = (b*HP + hp)*HP + wpp;
    uint4 z = {0,0,0,0};
    uint4* c4 = (uint4*)catT  + (size_t)pix*16;
    uint4* w4 = (uint4*)w11T  + (size_t)pix*8;
    uint4* o4 = (uint4*)out3T + (size_t)pix*8;
    #pragma unroll
    for (int k = 0; k < 16; ++k) c4[k] = z;
    #pragma unroll
    for (int k = 0; k < 8; ++k){ w4[k] = z; o4[k] = z; }
  }
  // ---- weight reorders ----
  const int total = 147456 + 331776 + 36864;
  for (int i = r*256 + t; i < total; i += STR){
    float v; bfu* dst;
    if (i < 147456){
      int tap = i >> 14, och = (i >> 7) & 127, cin = i & 127;
      v = (och < 64) ? w11w[(och*128 + cin)*9 + tap] : w21w[((och-64)*128 + cin)*9 + tap];
      dst = A11 + i;
    } else if (i < 147456 + 331776){
      int i2 = i - 147456;
      int g = i2 >> 12, tt = g/9, tap2 = g%9;
      int c = (i2 >> 6) & 63, j = i2 & 63;
      v = w12w[((c*9 + tt)*64 + j)*9 + tap2];
      dst = A12 + i2;
    } else {
      int i3 = i - (147456 + 331776);
      int tap2 = i3 >> 12, oc = (i3 >> 6) & 63, j = i3 & 63;
      v = w3w[(oc*64 + j)*9 + tap2];
      dst = A3 + i3;
    }
    *dst = f2bf(v);
  }
}

// ---------------- k1: conv11 + conv21 (r13 exact) ----------------
__global__ __launch_bounds__(256) void k1_conv(
    const bfu* __restrict__ catT, const bfu* __restrict__ A11,
    const float* __restrict__ b11, const float* __restrict__ b21,
    bfu* __restrict__ w11T, float* __restrict__ poolP){
  __shared__ bfu ldsC[180*128];              // 46,080 B, swizzled cat tile
  __shared__ bfu ldsA[2*8192];               // 32,768 B: 2 bufs x 1024 uint4
  __shared__ float statsF[128];              //    512 B
  int tid = threadIdx.x;
  int b = blockIdx.y, tile = blockIdx.x;     // 0..127
  int h0 = (tile >> 3)*8, w0 = (tile & 7)*16;

  int wid = tid >> 6, l = tid & 63, lg = l >> 4, pc = l & 15;
  int wm = wid >> 1, wn = wid & 1;
  int pcT = tid & 15, lgT = (tid >> 4) & 3;

  const uint4* A4 = (const uint4*)A11;       // [tap][row128][16]
  uint4* ldsA4 = (uint4*)ldsA;

  #pragma unroll
  for (int k = 0; k < 4; ++k){
    int q = k*4 + wid;
    int row = (q >> 1)*16 + pcT;
    gload_lds16(A4 + row*16 + (q&1)*4 + lgT, ldsA4 + k*256 + wid*64);
  }

  const uint4* catT4 = (const uint4*)catT;
  for (int s = tid; s < 180*16; s += 256){
    int cell = s >> 4, sub = s & 15;
    int th = cell/18, tw = cell - th*18;
    uint4 v = catT4[(((b*HP + h0+th)*HP) + (w0+tw))*16 + sub];
    *(uint4*)&ldsC[cell*128 + ((sub*8) ^ ((cell&7)<<3))] = v;
  }
  __syncthreads();

  f32x4 acc[4][4];
  #pragma unroll
  for (int i = 0; i < 4; ++i)
    #pragma unroll
    for (int j = 0; j < 4; ++j) acc[i][j] = f32x4{0.f,0.f,0.f,0.f};

  int cur = 0;
  #pragma unroll 1
  for (int cc = 0; cc < 18; ++cc){
    int tap = cc >> 1, p = cc & 1;
    if (cc < 17){
      int cc1 = cc + 1, tap1 = cc1 >> 1, p1 = cc1 & 1;
      #pragma unroll
      for (int k = 0; k < 4; ++k){
        int q = k*4 + wid;
        int row = (q >> 1)*16 + pcT;
        gload_lds16(A4 + tap1*2048 + row*16 + p1*8 + (q&1)*4 + lgT,
                    ldsA4 + (cur^1)*1024 + k*256 + wid*64);
      }
    }
    int kh = (tap >= 6) ? 2 : ((tap >= 3) ? 1 : 0);
    int kw = tap - kh*3;
    #pragma unroll
    for (int jq = 0; jq < 2; ++jq){
      int jc = p*2 + jq;
      bf16x8 a[4], bb[4];
      #pragma unroll
      for (int fm = 0; fm < 4; ++fm)
        a[fm] = __builtin_bit_cast(bf16x8, ldsA4[cur*1024 + ((wm*4 + fm)*2 + jq)*64 + l]);
      #pragma unroll
      for (int fn = 0; fn < 4; ++fn){
        int cell = (wn*4 + fn + kh)*18 + (pc + kw);
        bb[fn] = ldsfrag(&ldsC[cell*128 + ((jc*32 + lg*8) ^ ((cell&7)<<3))]);
      }
      #pragma unroll
      for (int fm = 0; fm < 4; ++fm)
        #pragma unroll
        for (int fn = 0; fn < 4; ++fn)
          acc[fm][fn] = mfma16(a[fm], bb[fn], acc[fm][fn]);
    }
    __syncthreads();
    cur ^= 1;
  }

  if (wm == 0){
    #pragma unroll
    for (int fm = 0; fm < 4; ++fm)
      #pragma unroll
      for (int r = 0; r < 4; ++r){
        int och = fm*16 + lg*4 + r;
        float bias = b11[och];
        #pragma unroll
        for (int fn = 0; fn < 4; ++fn){
          float v = acc[fm][fn][r] + bias;
          v = v > 0.f ? v : 0.f;
          int px = wn*64 + fn*16 + pc;
          ldsC[px*72 + och] = f2bf(v);
        }
      }
  } else {
    #pragma unroll
    for (int fm = 0; fm < 4; ++fm)
      #pragma unroll
      for (int r = 0; r < 4; ++r){
        int cw = fm*16 + lg*4 + r;
        float bias = b21[cw];
        float s = 0.f;
        #pragma unroll
        for (int fn = 0; fn < 4; ++fn){
          float v = acc[fm][fn][r] + bias;
          s += (v > 0.f ? v : 0.f);
        }
        s += __shfl_xor(s,1); s += __shfl_xor(s,2); s += __shfl_xor(s,4); s += __shfl_xor(s,8);
        if (pc == 0) statsF[wn*64 + cw] = s;
      }
  }
  __syncthreads();

  if (wid < 2){
    int px = tid;
    int h = h0 + (px >> 4), w = w0 + (px & 15);
    uint4* dst = (uint4*)w11T + (((b*HP + h+1)*HP) + (w+1))*8;
    const uint4* srcT = (const uint4*)&ldsC[px*72];
    #pragma unroll
    for (int k = 0; k < 8; ++k) dst[k] = srcT[k];
  }
  if (tid < 64)
    poolP[(b*128 + tile)*64 + tid] = statsF[tid] + statsF[64 + tid];
}

// ---------------- k2: pooled mean + w22 GEMV fused (bf16 output) ----------------
__global__ __launch_bounds__(256) void k2_w22(
    const float* __restrict__ poolP, const float* __restrict__ W22,
    const float* __restrict__ b22, bfu* __restrict__ w22bf){
  __shared__ float pl[64];
  int b = blockIdx.x >> 4, og = blockIdx.x & 15;
  int t = threadIdx.x;
  if (t < 64){
    float s = 0.f;
    for (int tile = 0; tile < 128; ++tile) s += poolP[(b*128 + tile)*64 + t];
    pl[t] = s * (1.f/16384.f);
  }
  __syncthreads();
  int o = og*256 + t;
  float acc = b22[o];
  #pragma unroll 4
  for (int c = 0; c < 64; ++c) acc += pl[c]*W22[o*64 + c];
  w22bf[b*4096 + o] = f2bf(acc);
}

// ---------------- k3: fused conv12 + local_conv + BN1 stats (r10/r13 exact) ----------------
__global__ __launch_bounds__(256) void k3_fused(
    const bfu* __restrict__ w11T, const bfu* __restrict__ catT,
    const bfu* __restrict__ A12, const float* __restrict__ b12,
    float* __restrict__ out1, float* __restrict__ st1){
  __shared__ bfu ldsW[180*64];               // 23,040 B, swizzled (10x18 cells)
  __shared__ bfu ldsA[2*1536*8];             // 49,152 B: 2 bufs x 3 slices
  __shared__ float b12f[576];                //  2,304 B
  __shared__ float wp[512];                  //  2,048 B   (total 76,544 B)
  int tid = threadIdx.x;
  int b = blockIdx.y, tile = blockIdx.x;     // 0..127
  int h0 = (tile >> 3)*8, w0 = (tile & 7)*16;

  int wid = tid >> 6, l = tid & 63, lg = l >> 4, pc = l & 15;
  int w2 = wid*2;

  const uint4* A4 = (const uint4*)A12;
  uint4* ldsA4 = (uint4*)ldsA;
  int srcA = ((tid >> 7)*16 + (tid & 15))*8 + ((tid >> 6) & 1)*4 + ((tid >> 4) & 3);
  uint4* dstBase = ldsA4 + wid*64;

  {
    const uint4* sb = A4 + srcA;
    #pragma unroll
    for (int q = 0; q < 6; ++q)
      gload_lds16(sb + (q>>1)*512 + ((q&1)<<8), dstBase + (q>>1)*512 + ((q&1)<<8));
  }

  const uint4* w11T4 = (const uint4*)w11T;
  for (int s = tid; s < 180*8; s += 256){
    int cell = s >> 3, sub = s & 7;
    int th = cell/18, tw = cell - th*18;
    uint4 v = w11T4[(((b*HP + h0+th)*HP) + (w0+tw))*8 + sub];
    *(uint4*)&ldsW[cell*64 + ((sub*8) ^ ((cell&7)<<3))] = v;
  }
  for (int i = tid; i < 576; i += 256) b12f[i] = b12[i];
  __syncthreads();

  f32x4 oacc[4][2];
  #pragma unroll
  for (int i = 0; i < 4; ++i){ oacc[i][0] = f32x4{0.f,0.f,0.f,0.f}; oacc[i][1] = f32x4{0.f,0.f,0.f,0.f}; }
  f32x4 y[4][2];
  int cur = 0;

  #pragma unroll 1
  for (int cc = 0; cc < 27; ++cc){
    int tt = cc/3, m3 = cc - tt*3;
    if (cc < 26){
      const uint4* sb = A4 + (size_t)((cc+1)*3)*512 + srcA;
      uint4* db = dstBase + (cur^1)*1536;
      #pragma unroll
      for (int q = 0; q < 6; ++q)
        gload_lds16(sb + (q>>1)*512 + ((q&1)<<8), db + (q>>1)*512 + ((q&1)<<8));
    }
    if (m3 == 0){
      #pragma unroll
      for (int i = 0; i < 4; ++i){ y[i][0] = f32x4{0.f,0.f,0.f,0.f}; y[i][1] = f32x4{0.f,0.f,0.f,0.f}; }
    }
    #pragma unroll
    for (int t3 = 0; t3 < 3; ++t3){
      #pragma unroll
      for (int jc = 0; jc < 2; ++jc){
        bf16x8 a[4], bbf[2];
        #pragma unroll
        for (int fm = 0; fm < 4; ++fm)
          a[fm] = __builtin_bit_cast(bf16x8, ldsA4[cur*1536 + t3*512 + (fm*2 + jc)*64 + l]);
        #pragma unroll
        for (int fn = 0; fn < 2; ++fn){
          int cell = (w2 + fn + m3)*18 + (pc + t3);
          bbf[fn] = ldsfrag(&ldsW[cell*64 + ((jc*32 + lg*8) ^ ((cell&7)<<3))]);
        }
        #pragma unroll
        for (int fm = 0; fm < 4; ++fm)
          #pragma unroll
          for (int fn = 0; fn < 2; ++fn)
            y[fm][fn] = mfma16(a[fm], bbf[fn], y[fm][fn]);
      }
    }
    __syncthreads();
    if (m3 == 2){
      int dh = tt/3, dw = tt - dh*3;
      #pragma unroll
      for (int fn = 0; fn < 2; ++fn){
        const bfu* base = catT + ((size_t)((b*HP + h0 + w2 + fn + dh)*HP) + (w0 + pc + dw))*128 + lg*4;
        #pragma unroll
        for (int fm = 0; fm < 4; ++fm){
          ushort4 iv = *(const ushort4*)(base + fm*16);
          float i0 = bf2f(iv.x), i1 = bf2f(iv.y), i2 = bf2f(iv.z), i3 = bf2f(iv.w);
          int c = fm*16 + lg*4;
          oacc[fm][fn][0] += i0 * (y[fm][fn][0] + b12f[(c+0)*9 + tt]);
          oacc[fm][fn][1] += i1 * (y[fm][fn][1] + b12f[(c+1)*9 + tt]);
          oacc[fm][fn][2] += i2 * (y[fm][fn][2] + b12f[(c+2)*9 + tt]);
          oacc[fm][fn][3] += i3 * (y[fm][fn][3] + b12f[(c+3)*9 + tt]);
        }
      }
    }
    cur ^= 1;
  }

  #pragma unroll
  for (int fm = 0; fm < 4; ++fm)
    #pragma unroll
    for (int r = 0; r < 4; ++r){
      int c = fm*16 + lg*4 + r;
      float s = 0.f, ss = 0.f;
      #pragma unroll
      for (int fn = 0; fn < 2; ++fn){
        float v = oacc[fm][fn][r];
        out1[((b*64 + c)*128 + h0 + w2 + fn)*128 + (w0 + pc)] = v;
        s += v; ss += v*v;
      }
      s += __shfl_xor(s,1); s += __shfl_xor(s,2); s += __shfl_xor(s,4); s += __shfl_xor(s,8);
      ss += __shfl_xor(ss,1); ss += __shfl_xor(ss,2); ss += __shfl_xor(ss,4); ss += __shfl_xor(ss,8);
      if (pc == 0){ wp[(wid*64 + c)*2] = s; wp[(wid*64 + c)*2 + 1] = ss; }
    }
  __syncthreads();
  if (tid < 64){
    float s = 0.f, ss = 0.f;
    #pragma unroll
    for (int w = 0; w < 4; ++w){ s += wp[(w*64 + tid)*2]; ss += wp[(w*64 + tid)*2 + 1]; }
    int blin = b*128 + tile;
    st1[(blin*64 + tid)*2] = s; st1[(blin*64 + tid)*2 + 1] = ss;
  }
}

// ---------------- k4: einsum MFMA GEMM + inline BN1 reduce + BN2 stats ----------------
__global__ __launch_bounds__(256) void k4_einsum(
    const float* __restrict__ out1, const bfu* __restrict__ w22bf,
    const float* __restrict__ st1, const float* __restrict__ lgm,
    const float* __restrict__ lbt, float* __restrict__ out2, float* __restrict__ st2){
  __shared__ bfu ldsX[256*72];               // [px][j], 144B rows
  __shared__ float a1[64], be1[64];
  __shared__ float wp[512];
  int tid = threadIdx.x;
  int b = blockIdx.y, chunk = blockIdx.x;    // 64 chunks of 256 px

  {                                          // inline bn1 = reduce(st1, 512 blocks)
    int c = tid & 63, kk = tid >> 6;
    float s = 0.f, ss = 0.f;
    for (int k = kk; k < 512; k += 4){
      float2 v = *(const float2*)&st1[(k*64 + c)*2];
      s += v.x; ss += v.y;
    }
    wp[tid*2] = s; wp[tid*2 + 1] = ss;
    __syncthreads();
    if (tid < 64){
      #pragma unroll
      for (int q = 1; q < 4; ++q){ s += wp[(q*64 + tid)*2]; ss += wp[(q*64 + tid)*2 + 1]; }
      float mean = s/65536.f, var = ss/65536.f - mean*mean;
      float a = lgm[tid]*rsqrtf(var + EPSV);
      a1[tid] = a; be1[tid] = lbt[tid] - mean*a;
    }
    __syncthreads();
  }
  int p0 = chunk*256;

  {
    int px = tid;
    const float* src = out1 + (size_t)(b*64)*HW + p0 + px;
    #pragma unroll 1
    for (int j0 = 0; j0 < 64; j0 += 4){
      float x0 = src[(j0+0)*HW]; x0 = a1[j0+0]*x0 + be1[j0+0]; x0 = x0 > 0.f ? x0 : 0.f;
      float x1 = src[(j0+1)*HW]; x1 = a1[j0+1]*x1 + be1[j0+1]; x1 = x1 > 0.f ? x1 : 0.f;
      float x2 = src[(j0+2)*HW]; x2 = a1[j0+2]*x2 + be1[j0+2]; x2 = x2 > 0.f ? x2 : 0.f;
      float x3 = src[(j0+3)*HW]; x3 = a1[j0+3]*x3 + be1[j0+3]; x3 = x3 > 0.f ? x3 : 0.f;
      ushort4 pk; pk.x = f2bf(x0); pk.y = f2bf(x1); pk.z = f2bf(x2); pk.w = f2bf(x3);
      *(ushort4*)&ldsX[px*72 + j0] = pk;
    }
  }
  __syncthreads();

  int wid = tid >> 6, l = tid & 63, lg = l >> 4, pc = l & 15;
  const uint4* W4 = (const uint4*)w22bf;
  f32x4 acc[4][4];
  #pragma unroll
  for (int i = 0; i < 4; ++i)
    #pragma unroll
    for (int j = 0; j < 4; ++j) acc[i][j] = f32x4{0.f,0.f,0.f,0.f};

  #pragma unroll
  for (int jc = 0; jc < 2; ++jc){
    bf16x8 a[4], bb[4];
    #pragma unroll
    for (int fm = 0; fm < 4; ++fm)
      a[fm] = __builtin_bit_cast(bf16x8, W4[b*512 + (fm*16 + pc)*8 + jc*4 + lg]);
    #pragma unroll
    for (int fn = 0; fn < 4; ++fn)
      bb[fn] = ldsfrag(&ldsX[(wid*64 + fn*16 + pc)*72 + jc*32 + lg*8]);
    #pragma unroll
    for (int fm = 0; fm < 4; ++fm)
      #pragma unroll
      for (int fn = 0; fn < 4; ++fn)
        acc[fm][fn] = mfma16(a[fm], bb[fn], acc[fm][fn]);
  }

  #pragma unroll
  for (int fm = 0; fm < 4; ++fm)
    #pragma unroll
    for (int r = 0; r < 4; ++r){
      int i = fm*16 + lg*4 + r;
      float s = 0.f, ss = 0.f;
      #pragma unroll
      for (int fn = 0; fn < 4; ++fn){
        int px = wid*64 + fn*16 + pc;
        float v = acc[fm][fn][r];
        out2[(b*64 + i)*HW + p0 + px] = v;
        s += v; ss += v*v;
      }
      s += __shfl_xor(s,1); s += __shfl_xor(s,2); s += __shfl_xor(s,4); s += __shfl_xor(s,8);
      ss += __shfl_xor(ss,1); ss += __shfl_xor(ss,2); ss += __shfl_xor(ss,4); ss += __shfl_xor(ss,8);
      if (pc == 0){ wp[(wid*64 + i)*2] = s; wp[(wid*64 + i)*2 + 1] = ss; }
    }
  __syncthreads();
  if (tid < 64){
    float s = 0.f, ss = 0.f;
    #pragma unroll
    for (int w = 0; w < 4; ++w){ s += wp[(w*64 + tid)*2]; ss += wp[(w*64 + tid)*2 + 1]; }
    int blin = b*64 + chunk;
    st2[(blin*64 + tid)*2] = s; st2[(blin*64 + tid)*2 + 1] = ss;
  }
}

// ---------------- k4c: inline BN2 reduce + out3T = relu(bn2(out2)) NHWC bf16 ----------------
__global__ __launch_bounds__(256) void k4c_out3(
    const float* __restrict__ out2, const float* __restrict__ st2,
    const float* __restrict__ brg, const float* __restrict__ brb, bfu* out3T){
  __shared__ bfu lds[128*72];
  __shared__ float red[512];
  __shared__ float sa[64], sb[64];
  int b = blockIdx.y, h = blockIdx.x;        // grid (128,4)
  int t = threadIdx.x;

  {                                          // inline bn2 = reduce(st2, 256 blocks)
    int c = t & 63, kk = t >> 6;
    float s = 0.f, ss = 0.f;
    for (int k = kk; k < 256; k += 4){
      float2 v = *(const float2*)&st2[(k*64 + c)*2];
      s += v.x; ss += v.y;
    }
    red[t*2] = s; red[t*2 + 1] = ss;
    __syncthreads();
    if (t < 64){
      #pragma unroll
      for (int q = 1; q < 4; ++q){ s += red[(q*64 + t)*2]; ss += red[(q*64 + t)*2 + 1]; }
      float mean = s/65536.f, var = ss/65536.f - mean*mean;
      float a = brg[t]*rsqrtf(var + EPSV);
      sa[t] = a; sb[t] = brb[t] - mean*a;
    }
    __syncthreads();
  }

  int px = t & 127, ch = (t >> 7)*32;
  #pragma unroll 1
  for (int cc = 0; cc < 32; cc += 4){
    int c = ch + cc;
    float x0 = out2[((b*64 + c+0) << 14) + (h << 7) + px];
    float x1 = out2[((b*64 + c+1) << 14) + (h << 7) + px];
    float x2 = out2[((b*64 + c+2) << 14) + (h << 7) + px];
    float x3 = out2[((b*64 + c+3) << 14) + (h << 7) + px];
    x0 = sa[c+0]*x0 + sb[c+0]; x0 = x0 > 0.f ? x0 : 0.f;
    x1 = sa[c+1]*x1 + sb[c+1]; x1 = x1 > 0.f ? x1 : 0.f;
    x2 = sa[c+2]*x2 + sb[c+2]; x2 = x2 > 0.f ? x2 : 0.f;
    x3 = sa[c+3]*x3 + sb[c+3]; x3 = x3 > 0.f ? x3 : 0.f;
    ushort4 pk; pk.x = f2bf(x0); pk.y = f2bf(x1); pk.z = f2bf(x2); pk.w = f2bf(x3);
    *(ushort4*)&lds[px*72 + c] = pk;
  }
  __syncthreads();
  uint4* dst = (uint4*)out3T;
  #pragma unroll
  for (int k = 0; k < 4; ++k){
    int idx = k*256 + t;                     // 0..1023
    int pix = idx >> 3, sub = idx & 7;
    uint4 v = *(const uint4*)&lds[pix*72 + sub*8];
    dst[((size_t)(b*HP + h+1)*HP + (pix+1))*8 + sub] = v;
  }
}

// ---------------- k5: conv3 (r13 exact) ----------------
__global__ __launch_bounds__(256) void k5_conv3(
    const bfu* __restrict__ out3T, const bfu* __restrict__ A3,
    float* __restrict__ outc, float* __restrict__ st3){
  __shared__ bfu lds[180*72];                // 10x18 cells, 25,920 B
  __shared__ float wp[512];
  int tid = threadIdx.x;
  int b = blockIdx.y, tile = blockIdx.x;     // 0..127
  int h0 = (tile >> 3)*8, w0 = (tile & 7)*16;
  const uint4* src4 = (const uint4*)out3T;
  for (int s = tid; s < 180*8; s += 256){
    int cell = s >> 3, sub = s & 7;
    int th = cell/18, tw = cell - th*18;
    *(uint4*)&lds[cell*72 + sub*8] = src4[(((b*HP + h0+th)*HP) + (w0+tw))*8 + sub];
  }
  __syncthreads();

  int wid = tid >> 6, l = tid & 63, lg = l >> 4, pc = l & 15;
  f32x4 acc[4][2];
  #pragma unroll
  for (int i = 0; i < 4; ++i){ acc[i][0] = f32x4{0.f,0.f,0.f,0.f}; acc[i][1] = f32x4{0.f,0.f,0.f,0.f}; }
  const uint4* A4 = (const uint4*)A3;
  #pragma unroll 3
  for (int tap2 = 0; tap2 < 9; ++tap2){
    int kh = tap2/3, kw = tap2 - kh*3;
    #pragma unroll
    for (int jc = 0; jc < 2; ++jc){
      bf16x8 a[4], bb[2];
      #pragma unroll
      for (int fm = 0; fm < 4; ++fm)
        a[fm] = __builtin_bit_cast(bf16x8, A4[tap2*512 + (fm*16 + pc)*8 + jc*4 + lg]);
      #pragma unroll
      for (int fn = 0; fn < 2; ++fn){
        int cell = (wid*2 + fn + kh)*18 + (pc + kw);
        bb[fn] = ldsfrag(&lds[cell*72 + jc*32 + lg*8]);
      }
      #pragma unroll
      for (int fm = 0; fm < 4; ++fm)
        #pragma unroll
        for (int fn = 0; fn < 2; ++fn)
          acc[fm][fn] = mfma16(a[fm], bb[fn], acc[fm][fn]);
    }
  }
  #pragma unroll
  for (int fm = 0; fm < 4; ++fm)
    #pragma unroll
    for (int r = 0; r < 4; ++r){
      int c = fm*16 + lg*4 + r;
      float s = 0.f, ss = 0.f;
      #pragma unroll
      for (int fn = 0; fn < 2; ++fn){
        int pr = wid*2 + fn;
        float v = acc[fm][fn][r];
        outc[((b*64 + c)*128 + h0 + pr)*128 + (w0 + pc)] = v;
        s += v; ss += v*v;
      }
      s += __shfl_xor(s,1); s += __shfl_xor(s,2); s += __shfl_xor(s,4); s += __shfl_xor(s,8);
      ss += __shfl_xor(ss,1); ss += __shfl_xor(ss,2); ss += __shfl_xor(ss,4); ss += __shfl_xor(ss,8);
      if (pc == 0){ wp[(wid*64 + c)*2] = s; wp[(wid*64 + c)*2 + 1] = ss; }
    }
  __syncthreads();
  if (tid < 64){
    float s = 0.f, ss = 0.f;
    #pragma unroll
    for (int w = 0; w < 4; ++w){ s += wp[(w*64 + tid)*2]; ss += wp[(w*64 + tid)*2 + 1]; }
    int blin = b*128 + tile;
    st3[(blin*64 + tid)*2] = s; st3[(blin*64 + tid)*2 + 1] = ss;
  }
}

// ---------------- k6: inline BN3 reduce + final relu(bn3(x)) in place ----------------
__global__ __launch_bounds__(256) void k6_final(
    float4* __restrict__ out, const float* __restrict__ st3,
    const float* __restrict__ c3g, const float* __restrict__ c3b){
  __shared__ float red[512];
  __shared__ float sa[64], sb[64];
  int tid = threadIdx.x;
  {                                          // inline bn3 = reduce(st3, 512 blocks)
    int c = tid & 63, kk = tid >> 6;
    float s = 0.f, ss = 0.f;
    for (int k = kk; k < 512; k += 4){
      float2 v = *(const float2*)&st3[(k*64 + c)*2];
      s += v.x; ss += v.y;
    }
    red[tid*2] = s; red[tid*2 + 1] = ss;
    __syncthreads();
    if (tid < 64){
      #pragma unroll
      for (int q = 1; q < 4; ++q){ s += red[(q*64 + tid)*2]; ss += red[(q*64 + tid)*2 + 1]; }
      float mean = s/65536.f, var = ss/65536.f - mean*mean;
      float a = c3g[tid]*rsqrtf(var + EPSV);
      sa[tid] = a; sb[tid] = c3b[tid] - mean*a;
    }
    __syncthreads();
  }
  const int total4 = 4*64*HW/4;              // 1,048,576
  for (int i = blockIdx.x*256 + tid; i < total4; i += 256*256){
    int c = (i >> 12) & 63;
    float a = sa[c], be = sb[c];
    float4 x = out[i];
    x.x = a*x.x + be; x.x = x.x > 0.f ? x.x : 0.f;
    x.y = a*x.y + be; x.y = x.y > 0.f ? x.y : 0.f;
    x.z = a*x.z + be; x.z = x.z > 0.f ? x.z : 0.f;
    x.w = a*x.w + be; x.w = x.w > 0.f ? x.w : 0.f;
    out[i] = x;
  }
}

extern "C" void kernel_launch(void* const* d_in, const int* in_sizes, int n_in,
                              void* d_out, int out_size, void* d_ws, size_t ws_size,
                              hipStream_t stream){
  const float* inp  = (const float*)d_in[0];
  const float* wgt  = (const float*)d_in[1];
  const float* w11w = (const float*)d_in[2];
  const float* b11  = (const float*)d_in[3];
  const float* w12w = (const float*)d_in[4];
  const float* b12  = (const float*)d_in[5];
  const float* w21w = (const float*)d_in[6];
  const float* b21  = (const float*)d_in[7];
  const float* W22  = (const float*)d_in[8];
  const float* b22  = (const float*)d_in[9];
  const float* lg   = (const float*)d_in[10];
  const float* lb   = (const float*)d_in[11];
  const float* brg  = (const float*)d_in[12];
  const float* brb  = (const float*)d_in[13];
  const float* w3w  = (const float*)d_in[14];
  const float* c3g  = (const float*)d_in[15];
  const float* c3b  = (const float*)d_in[16];

  if (ws_size < 53200000) return;

  char* ws = (char*)d_ws;
  bfu*   catT  = (bfu*)(ws);                     // 17,305,600
  bfu*   w11T  = (bfu*)(ws + 17305600);          //  8,652,800
  bfu*   out3T = (bfu*)(ws + 25958400);          //  8,652,800
  bfu*   A11   = (bfu*)(ws + 34611200);          //    294,912
  bfu*   A12   = (bfu*)(ws + 34906112);          //    663,552
  bfu*   A3    = (bfu*)(ws + 35569664);          //     73,728
  float* out1  = (float*)(ws + 35643392);        // 16,777,216
  float* poolP = (float*)(ws + 52420608);        //    131,072
  bfu*   w22bf = (bfu*)(ws + 52552704);          //     32,768
  float* st13  = (float*)(ws + 52585472);        //    262,144 (st1 then st3 — disjoint in time)
  float* st2   = (float*)(ws + 52848128);        //    131,072
  float* outF  = (float*)d_out;

  k_prep   <<<dim3(134,4), dim3(256), 0, stream>>>(inp, wgt, w11w, w21w, w12w, w3w,
                                                   catT, A11, A12, A3, w11T, out3T);
  k1_conv  <<<dim3(128,4), dim3(256), 0, stream>>>(catT, A11, b11, b21, w11T, poolP);
  k2_w22   <<<dim3(64),    dim3(256), 0, stream>>>(poolP, W22, b22, w22bf);
  k3_fused <<<dim3(128,4), dim3(256), 0, stream>>>(w11T, catT, A12, b12, out1, st13);
  k4_einsum<<<dim3(64,4),  dim3(256), 0, stream>>>(out1, w22bf, st13, lg, lb, outF, st2);
  k4c_out3 <<<dim3(128,4), dim3(256), 0, stream>>>(outF, st2, brg, brb, out3T);
  k5_conv3 <<<dim3(128,4), dim3(256), 0, stream>>>(out3T, A3, outF, st13);
  k6_final <<<dim3(256),   dim3(256), 0, stream>>>((float4*)outF, st13, c3g, c3b);
}

// Round 17
// 272.896 us; speedup vs baseline: 1.0832x; 1.0212x over previous
//
#include <hip/hip_runtime.h>

#define EPSV 1e-5f
#define HP 130            // padded H/W
#define HW 16384          // 128*128

typedef unsigned int u32;
typedef unsigned short bfu;                                    // bf16 storage
typedef __bf16 bf16x8 __attribute__((ext_vector_type(8)));
typedef float  f32x4  __attribute__((ext_vector_type(4)));

__device__ __forceinline__ bfu f2bf(float f){
  u32 u = __builtin_bit_cast(u32, f);
  return (bfu)((u + 0x7FFFu + ((u >> 16) & 1u)) >> 16);        // RNE
}
__device__ __forceinline__ float bf2f(bfu h){
  return __builtin_bit_cast(float, ((u32)h) << 16);
}
__device__ __forceinline__ f32x4 mfma16(bf16x8 a, bf16x8 b, f32x4 c){
  return __builtin_amdgcn_mfma_f32_16x16x32_bf16(a, b, c, 0, 0, 0);
}
__device__ __forceinline__ bf16x8 ldsfrag(const bfu* p){
  return __builtin_bit_cast(bf16x8, *(const uint4*)p);
}
// async global->LDS, 16B per lane; LDS dest = wave-uniform base + lane*16
__device__ __forceinline__ void gload_lds16(const uint4* g, uint4* l){
  __builtin_amdgcn_global_load_lds(
      (const __attribute__((address_space(1))) unsigned int*)g,
      (__attribute__((address_space(3))) unsigned int*)l, 16, 0, 0);
}

// ---------------- k_prep: zero borders + weight reorder + catT build (fused) ----------------
__global__ __launch_bounds__(256) void k_prep(
    const float* __restrict__ inp, const float* __restrict__ wgt,
    const float* __restrict__ w11w, const float* __restrict__ w21w,
    const float* __restrict__ w12w, const float* __restrict__ w3w,
    bfu* catT, bfu* A11, bfu* A12, bfu* A3, bfu* w11T, bfu* out3T){
  __shared__ bfu lds[128*136];
  int bx = blockIdx.x, by = blockIdx.y;
  int t = threadIdx.x;

  if (bx < 128){                             // ---- prep_cat ----
    int b = by, h = bx;
    int w = t & 127, c0 = t >> 7;
    #pragma unroll 1
    for (int c = c0; c < 128; c += 2){
      const float* src = (c < 64) ? inp + ((b*64 + c)*128 + h)*128
                                  : wgt + ((b*64 + (c-64))*128 + h)*128;
      lds[w*136 + c] = f2bf(src[w]);
    }
    __syncthreads();
    uint4* dst = (uint4*)catT;
    #pragma unroll
    for (int k = 0; k < 8; ++k){
      int idx = k*256 + t;
      int pix = idx >> 4, sub = idx & 15;
      uint4 v = *(const uint4*)&lds[pix*136 + sub*8];
      dst[(((b*HP + h+1)*HP) + (pix+1))*16 + sub] = v;
    }
    return;
  }

  int r = (bx - 128)*4 + by;                 // 0..23
  const int STR = 24*256;
  for (int i = r*256 + t; i < 4*516; i += STR){
    int b = i/516, rr = i - b*516;
    int hp, wpp;
    if (rr < 130){ hp = 0; wpp = rr; }
    else if (rr < 260){ hp = 129; wpp = rr - 130; }
    else { int r2 = rr - 260; hp = 1 + (r2 >> 1); wpp = (r2 & 1)*129; }
    int pix = (b*HP + hp)*HP + wpp;
    uint4 z = {0,0,0,0};
    uint4* c4 = (uint4*)catT  + (size_t)pix*16;
    uint4* w4 = (uint4*)w11T  + (size_t)pix*8;
    uint4* o4 = (uint4*)out3T + (size_t)pix*8;
    #pragma unroll
    for (int k = 0; k < 16; ++k) c4[k] = z;
    #pragma unroll
    for (int k = 0; k < 8; ++k){ w4[k] = z; o4[k] = z; }
  }
  const int total = 147456 + 331776 + 36864;
  for (int i = r*256 + t; i < total; i += STR){
    float v; bfu* dst;
    if (i < 147456){
      int tap = i >> 14, och = (i >> 7) & 127, cin = i & 127;
      v = (och < 64) ? w11w[(och*128 + cin)*9 + tap] : w21w[((och-64)*128 + cin)*9 + tap];
      dst = A11 + i;
    } else if (i < 147456 + 331776){
      int i2 = i - 147456;
      int g = i2 >> 12, tt = g/9, tap2 = g%9;
      int c = (i2 >> 6) & 63, j = i2 & 63;
      v = w12w[((c*9 + tt)*64 + j)*9 + tap2];
      dst = A12 + i2;
    } else {
      int i3 = i - (147456 + 331776);
      int tap2 = i3 >> 12, oc = (i3 >> 6) & 63, j = i3 & 63;
      v = w3w[(oc*64 + j)*9 + tap2];
      dst = A3 + i3;
    }
    *dst = f2bf(v);
  }
}

// ---------------- k1: conv11 + conv21 (r13 exact) ----------------
__global__ __launch_bounds__(256) void k1_conv(
    const bfu* __restrict__ catT, const bfu* __restrict__ A11,
    const float* __restrict__ b11, const float* __restrict__ b21,
    bfu* __restrict__ w11T, float* __restrict__ poolP){
  __shared__ bfu ldsC[180*128];              // 46,080 B, swizzled cat tile
  __shared__ bfu ldsA[2*8192];               // 32,768 B: 2 bufs x 1024 uint4
  __shared__ float statsF[128];              //    512 B
  int tid = threadIdx.x;
  int b = blockIdx.y, tile = blockIdx.x;     // 0..127
  int h0 = (tile >> 3)*8, w0 = (tile & 7)*16;

  int wid = tid >> 6, l = tid & 63, lg = l >> 4, pc = l & 15;
  int wm = wid >> 1, wn = wid & 1;
  int pcT = tid & 15, lgT = (tid >> 4) & 3;

  const uint4* A4 = (const uint4*)A11;       // [tap][row128][16]
  uint4* ldsA4 = (uint4*)ldsA;

  #pragma unroll
  for (int k = 0; k < 4; ++k){
    int q = k*4 + wid;
    int row = (q >> 1)*16 + pcT;
    gload_lds16(A4 + row*16 + (q&1)*4 + lgT, ldsA4 + k*256 + wid*64);
  }

  const uint4* catT4 = (const uint4*)catT;
  for (int s = tid; s < 180*16; s += 256){
    int cell = s >> 4, sub = s & 15;
    int th = cell/18, tw = cell - th*18;
    uint4 v = catT4[(((b*HP + h0+th)*HP) + (w0+tw))*16 + sub];
    *(uint4*)&ldsC[cell*128 + ((sub*8) ^ ((cell&7)<<3))] = v;
  }
  __syncthreads();

  f32x4 acc[4][4];
  #pragma unroll
  for (int i = 0; i < 4; ++i)
    #pragma unroll
    for (int j = 0; j < 4; ++j) acc[i][j] = f32x4{0.f,0.f,0.f,0.f};

  int cur = 0;
  #pragma unroll 1
  for (int cc = 0; cc < 18; ++cc){
    int tap = cc >> 1, p = cc & 1;
    if (cc < 17){
      int cc1 = cc + 1, tap1 = cc1 >> 1, p1 = cc1 & 1;
      #pragma unroll
      for (int k = 0; k < 4; ++k){
        int q = k*4 + wid;
        int row = (q >> 1)*16 + pcT;
        gload_lds16(A4 + tap1*2048 + row*16 + p1*8 + (q&1)*4 + lgT,
                    ldsA4 + (cur^1)*1024 + k*256 + wid*64);
      }
    }
    int kh = (tap >= 6) ? 2 : ((tap >= 3) ? 1 : 0);
    int kw = tap - kh*3;
    #pragma unroll
    for (int jq = 0; jq < 2; ++jq){
      int jc = p*2 + jq;
      bf16x8 a[4], bb[4];
      #pragma unroll
      for (int fm = 0; fm < 4; ++fm)
        a[fm] = __builtin_bit_cast(bf16x8, ldsA4[cur*1024 + ((wm*4 + fm)*2 + jq)*64 + l]);
      #pragma unroll
      for (int fn = 0; fn < 4; ++fn){
        int cell = (wn*4 + fn + kh)*18 + (pc + kw);
        bb[fn] = ldsfrag(&ldsC[cell*128 + ((jc*32 + lg*8) ^ ((cell&7)<<3))]);
      }
      #pragma unroll
      for (int fm = 0; fm < 4; ++fm)
        #pragma unroll
        for (int fn = 0; fn < 4; ++fn)
          acc[fm][fn] = mfma16(a[fm], bb[fn], acc[fm][fn]);
    }
    __syncthreads();
    cur ^= 1;
  }

  if (wm == 0){
    #pragma unroll
    for (int fm = 0; fm < 4; ++fm)
      #pragma unroll
      for (int r = 0; r < 4; ++r){
        int och = fm*16 + lg*4 + r;
        float bias = b11[och];
        #pragma unroll
        for (int fn = 0; fn < 4; ++fn){
          float v = acc[fm][fn][r] + bias;
          v = v > 0.f ? v : 0.f;
          int px = wn*64 + fn*16 + pc;
          ldsC[px*72 + och] = f2bf(v);
        }
      }
  } else {
    #pragma unroll
    for (int fm = 0; fm < 4; ++fm)
      #pragma unroll
      for (int r = 0; r < 4; ++r){
        int cw = fm*16 + lg*4 + r;
        float bias = b21[cw];
        float s = 0.f;
        #pragma unroll
        for (int fn = 0; fn < 4; ++fn){
          float v = acc[fm][fn][r] + bias;
          s += (v > 0.f ? v : 0.f);
        }
        s += __shfl_xor(s,1); s += __shfl_xor(s,2); s += __shfl_xor(s,4); s += __shfl_xor(s,8);
        if (pc == 0) statsF[wn*64 + cw] = s;
      }
  }
  __syncthreads();

  if (wid < 2){
    int px = tid;
    int h = h0 + (px >> 4), w = w0 + (px & 15);
    uint4* dst = (uint4*)w11T + (((b*HP + h+1)*HP) + (w+1))*8;
    const uint4* srcT = (const uint4*)&ldsC[px*72];
    #pragma unroll
    for (int k = 0; k < 8; ++k) dst[k] = srcT[k];
  }
  if (tid < 64)
    poolP[(b*128 + tile)*64 + tid] = statsF[tid] + statsF[64 + tid];
}

// ---------------- k2: pooled mean + w22 GEMV fused (bf16 output) ----------------
__global__ __launch_bounds__(256) void k2_w22(
    const float* __restrict__ poolP, const float* __restrict__ W22,
    const float* __restrict__ b22, bfu* __restrict__ w22bf){
  __shared__ float pl[64];
  int b = blockIdx.x >> 4, og = blockIdx.x & 15;
  int t = threadIdx.x;
  if (t < 64){
    float s = 0.f;
    for (int tile = 0; tile < 128; ++tile) s += poolP[(b*128 + tile)*64 + t];
    pl[t] = s * (1.f/16384.f);
  }
  __syncthreads();
  int o = og*256 + t;
  float acc = b22[o];
  #pragma unroll 4
  for (int c = 0; c < 64; ++c) acc += pl[c]*W22[o*64 + c];
  w22bf[b*4096 + o] = f2bf(acc);
}

// ---------------- k3: fused conv12 + local_conv + BN1 stats (r13 pipeline; bf16 out1) ----------------
__global__ __launch_bounds__(256) void k3_fused(
    const bfu* __restrict__ w11T, const bfu* __restrict__ catT,
    const bfu* __restrict__ A12, const float* __restrict__ b12,
    bfu* __restrict__ out1, float* __restrict__ st1){
  __shared__ bfu ldsW[180*64];               // 23,040 B, swizzled (10x18 cells)
  __shared__ bfu ldsA[2*1536*8];             // 49,152 B: 2 bufs x 3 slices
  __shared__ float b12f[576];                //  2,304 B
  __shared__ float wp[512];                  //  2,048 B   (total 76,544 B)
  int tid = threadIdx.x;
  int b = blockIdx.y, tile = blockIdx.x;     // 0..127
  int h0 = (tile >> 3)*8, w0 = (tile & 7)*16;

  int wid = tid >> 6, l = tid & 63, lg = l >> 4, pc = l & 15;
  int w2 = wid*2;

  const uint4* A4 = (const uint4*)A12;
  uint4* ldsA4 = (uint4*)ldsA;
  int srcA = ((tid >> 7)*16 + (tid & 15))*8 + ((tid >> 6) & 1)*4 + ((tid >> 4) & 3);
  uint4* dstBase = ldsA4 + wid*64;

  {
    const uint4* sb = A4 + srcA;
    #pragma unroll
    for (int q = 0; q < 6; ++q)
      gload_lds16(sb + (q>>1)*512 + ((q&1)<<8), dstBase + (q>>1)*512 + ((q&1)<<8));
  }

  const uint4* w11T4 = (const uint4*)w11T;
  for (int s = tid; s < 180*8; s += 256){
    int cell = s >> 3, sub = s & 7;
    int th = cell/18, tw = cell - th*18;
    uint4 v = w11T4[(((b*HP + h0+th)*HP) + (w0+tw))*8 + sub];
    *(uint4*)&ldsW[cell*64 + ((sub*8) ^ ((cell&7)<<3))] = v;
  }
  for (int i = tid; i < 576; i += 256) b12f[i] = b12[i];
  __syncthreads();

  f32x4 oacc[4][2];
  #pragma unroll
  for (int i = 0; i < 4; ++i){ oacc[i][0] = f32x4{0.f,0.f,0.f,0.f}; oacc[i][1] = f32x4{0.f,0.f,0.f,0.f}; }
  f32x4 y[4][2];
  int cur = 0;

  #pragma unroll 1
  for (int cc = 0; cc < 27; ++cc){
    int tt = cc/3, m3 = cc - tt*3;
    if (cc < 26){
      const uint4* sb = A4 + (size_t)((cc+1)*3)*512 + srcA;
      uint4* db = dstBase + (cur^1)*1536;
      #pragma unroll
      for (int q = 0; q < 6; ++q)
        gload_lds16(sb + (q>>1)*512 + ((q&1)<<8), db + (q>>1)*512 + ((q&1)<<8));
    }
    if (m3 == 0){
      #pragma unroll
      for (int i = 0; i < 4; ++i){ y[i][0] = f32x4{0.f,0.f,0.f,0.f}; y[i][1] = f32x4{0.f,0.f,0.f,0.f}; }
    }
    #pragma unroll
    for (int t3 = 0; t3 < 3; ++t3){
      #pragma unroll
      for (int jc = 0; jc < 2; ++jc){
        bf16x8 a[4], bbf[2];
        #pragma unroll
        for (int fm = 0; fm < 4; ++fm)
          a[fm] = __builtin_bit_cast(bf16x8, ldsA4[cur*1536 + t3*512 + (fm*2 + jc)*64 + l]);
        #pragma unroll
        for (int fn = 0; fn < 2; ++fn){
          int cell = (w2 + fn + m3)*18 + (pc + t3);
          bbf[fn] = ldsfrag(&ldsW[cell*64 + ((jc*32 + lg*8) ^ ((cell&7)<<3))]);
        }
        #pragma unroll
        for (int fm = 0; fm < 4; ++fm)
          #pragma unroll
          for (int fn = 0; fn < 2; ++fn)
            y[fm][fn] = mfma16(a[fm], bbf[fn], y[fm][fn]);
      }
    }
    __syncthreads();
    if (m3 == 2){
      int dh = tt/3, dw = tt - dh*3;
      #pragma unroll
      for (int fn = 0; fn < 2; ++fn){
        const bfu* base = catT + ((size_t)((b*HP + h0 + w2 + fn + dh)*HP) + (w0 + pc + dw))*128 + lg*4;
        #pragma unroll
        for (int fm = 0; fm < 4; ++fm){
          ushort4 iv = *(const ushort4*)(base + fm*16);
          float i0 = bf2f(iv.x), i1 = bf2f(iv.y), i2 = bf2f(iv.z), i3 = bf2f(iv.w);
          int c = fm*16 + lg*4;
          oacc[fm][fn][0] += i0 * (y[fm][fn][0] + b12f[(c+0)*9 + tt]);
          oacc[fm][fn][1] += i1 * (y[fm][fn][1] + b12f[(c+1)*9 + tt]);
          oacc[fm][fn][2] += i2 * (y[fm][fn][2] + b12f[(c+2)*9 + tt]);
          oacc[fm][fn][3] += i3 * (y[fm][fn][3] + b12f[(c+3)*9 + tt]);
        }
      }
    }
    cur ^= 1;
  }

  #pragma unroll
  for (int fm = 0; fm < 4; ++fm)
    #pragma unroll
    for (int r = 0; r < 4; ++r){
      int c = fm*16 + lg*4 + r;
      float s = 0.f, ss = 0.f;
      #pragma unroll
      for (int fn = 0; fn < 2; ++fn){
        float v = oacc[fm][fn][r];
        out1[((b*64 + c)*128 + h0 + w2 + fn)*128 + (w0 + pc)] = f2bf(v);
        s += v; ss += v*v;                   // stats from exact f32
      }
      s += __shfl_xor(s,1); s += __shfl_xor(s,2); s += __shfl_xor(s,4); s += __shfl_xor(s,8);
      ss += __shfl_xor(ss,1); ss += __shfl_xor(ss,2); ss += __shfl_xor(ss,4); ss += __shfl_xor(ss,8);
      if (pc == 0){ wp[(wid*64 + c)*2] = s; wp[(wid*64 + c)*2 + 1] = ss; }
    }
  __syncthreads();
  if (tid < 64){
    float s = 0.f, ss = 0.f;
    #pragma unroll
    for (int w = 0; w < 4; ++w){ s += wp[(w*64 + tid)*2]; ss += wp[(w*64 + tid)*2 + 1]; }
    int blin = b*128 + tile;
    st1[(blin*64 + tid)*2] = s; st1[(blin*64 + tid)*2 + 1] = ss;
  }
}

// ---------------- k4: einsum MFMA GEMM + inline BN1 reduce + BN2 stats (bf16 in/out) ----------------
__global__ __launch_bounds__(256) void k4_einsum(
    const bfu* __restrict__ out1, const bfu* __restrict__ w22bf,
    const float* __restrict__ st1, const float* __restrict__ lgm,
    const float* __restrict__ lbt, bfu* __restrict__ out2, float* __restrict__ st2){
  __shared__ bfu ldsX[256*72];               // [px][j], 144B rows
  __shared__ float a1[64], be1[64];
  __shared__ float wp[512];
  int tid = threadIdx.x;
  int b = blockIdx.y, chunk = blockIdx.x;    // 64 chunks of 256 px

  {                                          // inline bn1 = reduce(st1, 512 blocks)
    int c = tid & 63, kk = tid >> 6;
    float s = 0.f, ss = 0.f;
    for (int k = kk; k < 512; k += 4){
      float2 v = *(const float2*)&st1[(k*64 + c)*2];
      s += v.x; ss += v.y;
    }
    wp[tid*2] = s; wp[tid*2 + 1] = ss;
    __syncthreads();
    if (tid < 64){
      #pragma unroll
      for (int q = 1; q < 4; ++q){ s += wp[(q*64 + tid)*2]; ss += wp[(q*64 + tid)*2 + 1]; }
      float mean = s/65536.f, var = ss/65536.f - mean*mean;
      float a = lgm[tid]*rsqrtf(var + EPSV);
      a1[tid] = a; be1[tid] = lbt[tid] - mean*a;
    }
    __syncthreads();
  }
  int p0 = chunk*256;

  {
    int px = tid;
    const bfu* src = out1 + (size_t)(b*64)*HW + p0 + px;
    #pragma unroll 1
    for (int j0 = 0; j0 < 64; j0 += 4){
      float x0 = bf2f(src[(j0+0)*HW]); x0 = a1[j0+0]*x0 + be1[j0+0]; x0 = x0 > 0.f ? x0 : 0.f;
      float x1 = bf2f(src[(j0+1)*HW]); x1 = a1[j0+1]*x1 + be1[j0+1]; x1 = x1 > 0.f ? x1 : 0.f;
      float x2 = bf2f(src[(j0+2)*HW]); x2 = a1[j0+2]*x2 + be1[j0+2]; x2 = x2 > 0.f ? x2 : 0.f;
      float x3 = bf2f(src[(j0+3)*HW]); x3 = a1[j0+3]*x3 + be1[j0+3]; x3 = x3 > 0.f ? x3 : 0.f;
      ushort4 pk; pk.x = f2bf(x0); pk.y = f2bf(x1); pk.z = f2bf(x2); pk.w = f2bf(x3);
      *(ushort4*)&ldsX[px*72 + j0] = pk;
    }
  }
  __syncthreads();

  int wid = tid >> 6, l = tid & 63, lg = l >> 4, pc = l & 15;
  const uint4* W4 = (const uint4*)w22bf;
  f32x4 acc[4][4];
  #pragma unroll
  for (int i = 0; i < 4; ++i)
    #pragma unroll
    for (int j = 0; j < 4; ++j) acc[i][j] = f32x4{0.f,0.f,0.f,0.f};

  #pragma unroll
  for (int jc = 0; jc < 2; ++jc){
    bf16x8 a[4], bb[4];
    #pragma unroll
    for (int fm = 0; fm < 4; ++fm)
      a[fm] = __builtin_bit_cast(bf16x8, W4[b*512 + (fm*16 + pc)*8 + jc*4 + lg]);
    #pragma unroll
    for (int fn = 0; fn < 4; ++fn)
      bb[fn] = ldsfrag(&ldsX[(wid*64 + fn*16 + pc)*72 + jc*32 + lg*8]);
    #pragma unroll
    for (int fm = 0; fm < 4; ++fm)
      #pragma unroll
      for (int fn = 0; fn < 4; ++fn)
        acc[fm][fn] = mfma16(a[fm], bb[fn], acc[fm][fn]);
  }

  #pragma unroll
  for (int fm = 0; fm < 4; ++fm)
    #pragma unroll
    for (int r = 0; r < 4; ++r){
      int i = fm*16 + lg*4 + r;
      float s = 0.f, ss = 0.f;
      #pragma unroll
      for (int fn = 0; fn < 4; ++fn){
        int px = wid*64 + fn*16 + pc;
        float v = acc[fm][fn][r];
        out2[(b*64 + i)*HW + p0 + px] = f2bf(v);
        s += v; ss += v*v;                   // stats from exact f32
      }
      s += __shfl_xor(s,1); s += __shfl_xor(s,2); s += __shfl_xor(s,4); s += __shfl_xor(s,8);
      ss += __shfl_xor(ss,1); ss += __shfl_xor(ss,2); ss += __shfl_xor(ss,4); ss += __shfl_xor(ss,8);
      if (pc == 0){ wp[(wid*64 + i)*2] = s; wp[(wid*64 + i)*2 + 1] = ss; }
    }
  __syncthreads();
  if (tid < 64){
    float s = 0.f, ss = 0.f;
    #pragma unroll
    for (int w = 0; w < 4; ++w){ s += wp[(w*64 + tid)*2]; ss += wp[(w*64 + tid)*2 + 1]; }
    int blin = b*64 + chunk;
    st2[(blin*64 + tid)*2] = s; st2[(blin*64 + tid)*2 + 1] = ss;
  }
}

// ---------------- k4c: inline BN2 reduce + out3T = relu(bn2(out2)) NHWC bf16 ----------------
__global__ __launch_bounds__(256) void k4c_out3(
    const bfu* __restrict__ out2, const float* __restrict__ st2,
    const float* __restrict__ brg, const float* __restrict__ brb, bfu* out3T){
  __shared__ bfu lds[128*72];
  __shared__ float red[512];
  __shared__ float sa[64], sb[64];
  int b = blockIdx.y, h = blockIdx.x;        // grid (128,4)
  int t = threadIdx.x;

  {                                          // inline bn2 = reduce(st2, 256 blocks)
    int c = t & 63, kk = t >> 6;
    float s = 0.f, ss = 0.f;
    for (int k = kk; k < 256; k += 4){
      float2 v = *(const float2*)&st2[(k*64 + c)*2];
      s += v.x; ss += v.y;
    }
    red[t*2] = s; red[t*2 + 1] = ss;
    __syncthreads();
    if (t < 64){
      #pragma unroll
      for (int q = 1; q < 4; ++q){ s += red[(q*64 + t)*2]; ss += red[(q*64 + t)*2 + 1]; }
      float mean = s/65536.f, var = ss/65536.f - mean*mean;
      float a = brg[t]*rsqrtf(var + EPSV);
      sa[t] = a; sb[t] = brb[t] - mean*a;
    }
    __syncthreads();
  }

  int px = t & 127, ch = (t >> 7)*32;
  #pragma unroll 1
  for (int cc = 0; cc < 32; cc += 4){
    int c = ch + cc;
    float x0 = bf2f(out2[((b*64 + c+0) << 14) + (h << 7) + px]);
    float x1 = bf2f(out2[((b*64 + c+1) << 14) + (h << 7) + px]);
    float x2 = bf2f(out2[((b*64 + c+2) << 14) + (h << 7) + px]);
    float x3 = bf2f(out2[((b*64 + c+3) << 14) + (h << 7) + px]);
    x0 = sa[c+0]*x0 + sb[c+0]; x0 = x0 > 0.f ? x0 : 0.f;
    x1 = sa[c+1]*x1 + sb[c+1]; x1 = x1 > 0.f ? x1 : 0.f;
    x2 = sa[c+2]*x2 + sb[c+2]; x2 = x2 > 0.f ? x2 : 0.f;
    x3 = sa[c+3]*x3 + sb[c+3]; x3 = x3 > 0.f ? x3 : 0.f;
    ushort4 pk; pk.x = f2bf(x0); pk.y = f2bf(x1); pk.z = f2bf(x2); pk.w = f2bf(x3);
    *(ushort4*)&lds[px*72 + c] = pk;
  }
  __syncthreads();
  uint4* dst = (uint4*)out3T;
  #pragma unroll
  for (int k = 0; k < 4; ++k){
    int idx = k*256 + t;                     // 0..1023
    int pix = idx >> 3, sub = idx & 7;
    uint4 v = *(const uint4*)&lds[pix*72 + sub*8];
    dst[((size_t)(b*HP + h+1)*HP + (pix+1))*8 + sub] = v;
  }
}

// ---------------- k5: conv3 (r13 exact; bf16 output) ----------------
__global__ __launch_bounds__(256) void k5_conv3(
    const bfu* __restrict__ out3T, const bfu* __restrict__ A3,
    bfu* __restrict__ outc, float* __restrict__ st3){
  __shared__ bfu lds[180*72];                // 10x18 cells, 25,920 B
  __shared__ float wp[512];
  int tid = threadIdx.x;
  int b = blockIdx.y, tile = blockIdx.x;     // 0..127
  int h0 = (tile >> 3)*8, w0 = (tile & 7)*16;
  const uint4* src4 = (const uint4*)out3T;
  for (int s = tid; s < 180*8; s += 256){
    int cell = s >> 3, sub = s & 7;
    int th = cell/18, tw = cell - th*18;
    *(uint4*)&lds[cell*72 + sub*8] = src4[(((b*HP + h0+th)*HP) + (w0+tw))*8 + sub];
  }
  __syncthreads();

  int wid = tid >> 6, l = tid & 63, lg = l >> 4, pc = l & 15;
  f32x4 acc[4][2];
  #pragma unroll
  for (int i = 0; i < 4; ++i){ acc[i][0] = f32x4{0.f,0.f,0.f,0.f}; acc[i][1] = f32x4{0.f,0.f,0.f,0.f}; }
  const uint4* A4 = (const uint4*)A3;
  #pragma unroll 3
  for (int tap2 = 0; tap2 < 9; ++tap2){
    int kh = tap2/3, kw = tap2 - kh*3;
    #pragma unroll
    for (int jc = 0; jc < 2; ++jc){
      bf16x8 a[4], bb[2];
      #pragma unroll
      for (int fm = 0; fm < 4; ++fm)
        a[fm] = __builtin_bit_cast(bf16x8, A4[tap2*512 + (fm*16 + pc)*8 + jc*4 + lg]);
      #pragma unroll
      for (int fn = 0; fn < 2; ++fn){
        int cell = (wid*2 + fn + kh)*18 + (pc + kw);
        bb[fn] = ldsfrag(&lds[cell*72 + jc*32 + lg*8]);
      }
      #pragma unroll
      for (int fm = 0; fm < 4; ++fm)
        #pragma unroll
        for (int fn = 0; fn < 2; ++fn)
          acc[fm][fn] = mfma16(a[fm], bb[fn], acc[fm][fn]);
    }
  }
  #pragma unroll
  for (int fm = 0; fm < 4; ++fm)
    #pragma unroll
    for (int r = 0; r < 4; ++r){
      int c = fm*16 + lg*4 + r;
      float s = 0.f, ss = 0.f;
      #pragma unroll
      for (int fn = 0; fn < 2; ++fn){
        int pr = wid*2 + fn;
        float v = acc[fm][fn][r];
        outc[((b*64 + c)*128 + h0 + pr)*128 + (w0 + pc)] = f2bf(v);
        s += v; ss += v*v;                   // stats from exact f32
      }
      s += __shfl_xor(s,1); s += __shfl_xor(s,2); s += __shfl_xor(s,4); s += __shfl_xor(s,8);
      ss += __shfl_xor(ss,1); ss += __shfl_xor(ss,2); ss += __shfl_xor(ss,4); ss += __shfl_xor(ss,8);
      if (pc == 0){ wp[(wid*64 + c)*2] = s; wp[(wid*64 + c)*2 + 1] = ss; }
    }
  __syncthreads();
  if (tid < 64){
    float s = 0.f, ss = 0.f;
    #pragma unroll
    for (int w = 0; w < 4; ++w){ s += wp[(w*64 + tid)*2]; ss += wp[(w*64 + tid)*2 + 1]; }
    int blin = b*128 + tile;
    st3[(blin*64 + tid)*2] = s; st3[(blin*64 + tid)*2 + 1] = ss;
  }
}

// ---------------- k6: inline BN3 reduce + final relu(bn3(x)): bf16 in, f32 out ----------------
__global__ __launch_bounds__(256) void k6_final(
    const bfu* __restrict__ outc, float4* __restrict__ out,
    const float* __restrict__ st3, const float* __restrict__ c3g,
    const float* __restrict__ c3b){
  __shared__ float red[512];
  __shared__ float sa[64], sb[64];
  int tid = threadIdx.x;
  {                                          // inline bn3 = reduce(st3, 512 blocks)
    int c = tid & 63, kk = tid >> 6;
    float s = 0.f, ss = 0.f;
    for (int k = kk; k < 512; k += 4){
      float2 v = *(const float2*)&st3[(k*64 + c)*2];
      s += v.x; ss += v.y;
    }
    red[tid*2] = s; red[tid*2 + 1] = ss;
    __syncthreads();
    if (tid < 64){
      #pragma unroll
      for (int q = 1; q < 4; ++q){ s += red[(q*64 + tid)*2]; ss += red[(q*64 + tid)*2 + 1]; }
      float mean = s/65536.f, var = ss/65536.f - mean*mean;
      float a = c3g[tid]*rsqrtf(var + EPSV);
      sa[tid] = a; sb[tid] = c3b[tid] - mean*a;
    }
    __syncthreads();
  }
  const ushort4* src = (const ushort4*)outc;
  const int total4 = 4*64*HW/4;              // 1,048,576
  for (int i = blockIdx.x*256 + tid; i < total4; i += 256*256){
    int c = (i >> 12) & 63;
    float a = sa[c], be = sb[c];
    ushort4 u = src[i];
    float4 x;
    x.x = a*bf2f(u.x) + be; x.x = x.x > 0.f ? x.x : 0.f;
    x.y = a*bf2f(u.y) + be; x.y = x.y > 0.f ? x.y : 0.f;
    x.z = a*bf2f(u.z) + be; x.z = x.z > 0.f ? x.z : 0.f;
    x.w = a*bf2f(u.w) + be; x.w = x.w > 0.f ? x.w : 0.f;
    out[i] = x;
  }
}

extern "C" void kernel_launch(void* const* d_in, const int* in_sizes, int n_in,
                              void* d_out, int out_size, void* d_ws, size_t ws_size,
                              hipStream_t stream){
  const float* inp  = (const float*)d_in[0];
  const float* wgt  = (const float*)d_in[1];
  const float* w11w = (const float*)d_in[2];
  const float* b11  = (const float*)d_in[3];
  const float* w12w = (const float*)d_in[4];
  const float* b12  = (const float*)d_in[5];
  const float* w21w = (const float*)d_in[6];
  const float* b21  = (const float*)d_in[7];
  const float* W22  = (const float*)d_in[8];
  const float* b22  = (const float*)d_in[9];
  const float* lg   = (const float*)d_in[10];
  const float* lb   = (const float*)d_in[11];
  const float* brg  = (const float*)d_in[12];
  const float* brb  = (const float*)d_in[13];
  const float* w3w  = (const float*)d_in[14];
  const float* c3g  = (const float*)d_in[15];
  const float* c3b  = (const float*)d_in[16];

  if (ws_size < 53100000) return;

  char* ws = (char*)d_ws;
  bfu*   catT  = (bfu*)(ws);                     // 17,305,600
  bfu*   w11T  = (bfu*)(ws + 17305600);          //  8,652,800
  bfu*   out3T = (bfu*)(ws + 25958400);          //  8,652,800
  bfu*   A11   = (bfu*)(ws + 34611200);          //    294,912
  bfu*   A12   = (bfu*)(ws + 34906112);          //    663,552
  bfu*   A3    = (bfu*)(ws + 35569664);          //     73,728
  bfu*   out1b = (bfu*)(ws + 35643392);          //  8,388,608 (out1; later conv3_pre)
  bfu*   out2b = (bfu*)(ws + 44032000);          //  8,388,608
  float* poolP = (float*)(ws + 52420608);        //    131,072
  bfu*   w22bf = (bfu*)(ws + 52551680);          //     32,768
  float* st13  = (float*)(ws + 52584448);        //    262,144 (st1 then st3 — disjoint in time)
  float* st2   = (float*)(ws + 52846592);        //    131,072 -> end 52,977,664
  float* outF  = (float*)d_out;
  bfu*   outcb = out1b;                          // reuse: out1 consumed by k4 before k5 writes

  k_prep   <<<dim3(134,4), dim3(256), 0, stream>>>(inp, wgt, w11w, w21w, w12w, w3w,
                                                   catT, A11, A12, A3, w11T, out3T);
  k1_conv  <<<dim3(128,4), dim3(256), 0, stream>>>(catT, A11, b11, b21, w11T, poolP);
  k2_w22   <<<dim3(64),    dim3(256), 0, stream>>>(poolP, W22, b22, w22bf);
  k3_fused <<<dim3(128,4), dim3(256), 0, stream>>>(w11T, catT, A12, b12, out1b, st13);
  k4_einsum<<<dim3(64,4),  dim3(256), 0, stream>>>(out1b, w22bf, st13, lg, lb, out2b, st2);
  k4c_out3 <<<dim3(128,4), dim3(256), 0, stream>>>(out2b, st2, brg, brb, out3T);
  k5_conv3 <<<dim3(128,4), dim3(256), 0, stream>>>(out3T, A3, outcb, st13);
  k6_final <<<dim3(256),   dim3(256), 0, stream>>>(outcb, (float4*)outF, st13, c3g, c3b);
}